// Round 1
// baseline (1204.241 us; speedup 1.0000x reference)
//
#include <hip/hip_runtime.h>
#include <cstdint>
#include <cstddef>

// ---------------------------------------------------------------------------
// GraphAutoencoder: 2 layers of [4-head GATConv(128->128) -> concat -> Linear(512->128) -> ReLU]
// N=50000 nodes, E=800000 edges (+N self-loops). All fp32.
// ---------------------------------------------------------------------------

#define FDIM   128
#define HEADS  4
#define HCAT   512   // HEADS * FDIM

// ---------------- edge dtype detection (int64 vs int32) ---------------------
__global__ void k_detect(const void* ei, int E, int N, int* flag) {
    if (threadIdx.x == 0 && blockIdx.x == 0) {
        const long long* p = (const long long*)ei;
        int bad = 0;
        int n = E < 64 ? E : 64;
        for (int i = 0; i < n; ++i) {
            long long v = p[i];
            if (v < 0 || v >= (long long)N) bad = 1;
        }
        *flag = bad;  // 1 => buffer is int32, 0 => int64
    }
}

__device__ __forceinline__ int edge_at(const void* ei, int is32, long long pos) {
    return is32 ? ((const int*)ei)[pos] : (int)(((const long long*)ei)[pos]);
}

__global__ void k_zero_i32(int* p, int n) {
    int i = blockIdx.x * blockDim.x + threadIdx.x;
    if (i < n) p[i] = 0;
}

__global__ void k_count(const void* ei, const int* flag, int E, int N, int* deg) {
    int e = blockIdx.x * blockDim.x + threadIdx.x;
    int Etot = E + N;
    if (e >= Etot) return;
    int is32 = *flag;
    int dst = (e < E) ? edge_at(ei, is32, (long long)E + e) : (e - E);
    atomicAdd(&deg[dst], 1);
}

// single-block exclusive scan over deg[N] -> off[N+1]; cur[] = copy of off[0..N)
__global__ __launch_bounds__(1024) void k_scan(const int* deg, int* off, int* cur, int N) {
    __shared__ int ssum[1024];
    int tid = threadIdx.x;
    int chunk = (N + 1023) / 1024;
    int start = tid * chunk;
    int end = start + chunk;
    if (start > N) start = N;
    if (end > N) end = N;
    int s = 0;
    for (int i = start; i < end; ++i) s += deg[i];
    ssum[tid] = s;
    __syncthreads();
    for (int o = 1; o < 1024; o <<= 1) {
        int v = 0;
        if (tid >= o) v = ssum[tid - o];
        __syncthreads();
        ssum[tid] += v;
        __syncthreads();
    }
    int base = (tid == 0) ? 0 : ssum[tid - 1];
    for (int i = start; i < end; ++i) {
        off[i] = base;
        cur[i] = base;
        base += deg[i];
    }
    if (tid == 1023) off[N] = ssum[1023];
}

__global__ void k_fill(const void* ei, const int* flag, int E, int N, int* cur, int* csr) {
    int e = blockIdx.x * blockDim.x + threadIdx.x;
    int Etot = E + N;
    if (e >= Etot) return;
    int is32 = *flag;
    int src, dst;
    if (e < E) {
        src = edge_at(ei, is32, e);
        dst = edge_at(ei, is32, (long long)E + e);
    } else {
        src = e - E;
        dst = e - E;
    }
    int pos = atomicAdd(&cur[dst], 1);
    csr[pos] = src;
}

// ---------------- GEMM: C[M x NC] = A[M x K] * B, 64x64 tile ----------------
// HEADMODE=1: B is W[4][128][128]; column tile jc selects head = jc>>7, local col = jc&127.
// HEADMODE=0: B is linW[512][128] row-major, ldb=128. bias (len 128) + optional relu.
template <int RELU, int HEADMODE>
__global__ __launch_bounds__(256) void k_gemm64(
    const float* __restrict__ A, int lda,
    const float* __restrict__ B,
    const float* __restrict__ bias,
    float* __restrict__ C, int ldc, int M, int K) {
    const int BM = 64, BN = 64, BK = 16;
    __shared__ float As[BK][BM];
    __shared__ float Bs[BK][BN];
    int tid = threadIdx.x;
    int row0 = blockIdx.x * BM;
    int jc = blockIdx.y * BN;
    const float* Bp;
    int colbase;
    if (HEADMODE) {
        Bp = B + (size_t)(jc >> 7) * (FDIM * FDIM);
        colbase = jc & 127;
    } else {
        Bp = B;
        colbase = jc;
    }
    int tx = tid & 15, ty = tid >> 4;
    float acc[4][4] = {};
    for (int k0 = 0; k0 < K; k0 += BK) {
        {   // load A tile (64 rows x 16 k), float4 along k
            int r = tid >> 2;
            int kk = (tid & 3) * 4;
            const float* ap = A + (size_t)(row0 + r) * lda + k0 + kk;
            float4 v = make_float4(0.f, 0.f, 0.f, 0.f);
            if (row0 + r < M) v = *(const float4*)ap;
            As[kk + 0][r] = v.x;
            As[kk + 1][r] = v.y;
            As[kk + 2][r] = v.z;
            As[kk + 3][r] = v.w;
        }
        {   // load B tile (16 k x 64 cols), float4 along cols
            int kk = tid >> 4;
            int j = (tid & 15) * 4;
            const float* bp = Bp + (size_t)(k0 + kk) * 128 + colbase + j;
            *(float4*)&Bs[kk][j] = *(const float4*)bp;
        }
        __syncthreads();
#pragma unroll
        for (int kk = 0; kk < BK; ++kk) {
            float a[4], b[4];
            *(float4*)a = *(const float4*)&As[kk][ty * 4];
            *(float4*)b = *(const float4*)&Bs[kk][tx * 4];
#pragma unroll
            for (int i = 0; i < 4; ++i)
#pragma unroll
                for (int q = 0; q < 4; ++q) acc[i][q] += a[i] * b[q];
        }
        __syncthreads();
    }
#pragma unroll
    for (int i = 0; i < 4; ++i) {
        int r = row0 + ty * 4 + i;
        if (r >= M) continue;
#pragma unroll
        for (int q = 0; q < 4; ++q) {
            int j = jc + tx * 4 + q;
            float v = acc[i][q];
            if (bias) v += bias[j & 127];
            if (RELU) v = fmaxf(v, 0.f);
            C[(size_t)r * ldc + j] = v;
        }
    }
}

// ---------------- attention scores: ssrc/sdst[h][n] = Hcat[n,h*128:].a ------
__global__ __launch_bounds__(256) void k_scores(
    const float* __restrict__ Hcat, const float* __restrict__ asrc,
    const float* __restrict__ adst, float* __restrict__ ssrc,
    float* __restrict__ sdst, int N) {
    int n = blockIdx.x;
    int h = (threadIdx.x >> 6) & 3;
    int lane = threadIdx.x & 63;
    if (n >= N) return;
    const float* Hr = Hcat + (size_t)n * HCAT + h * FDIM;
    float a0 = Hr[lane], a1 = Hr[64 + lane];
    float s1 = a0 * asrc[h * FDIM + lane] + a1 * asrc[h * FDIM + 64 + lane];
    float s2 = a0 * adst[h * FDIM + lane] + a1 * adst[h * FDIM + 64 + lane];
    for (int o = 32; o; o >>= 1) {
        s1 += __shfl_xor(s1, o);
        s2 += __shfl_xor(s2, o);
    }
    if (lane == 0) {
        ssrc[h * N + n] = s1;
        sdst[h * N + n] = s2;
    }
}

// ---------------- per-dst segment softmax + aggregate, 1 wave/node ----------
__global__ __launch_bounds__(64) void k_aggregate(
    const float* __restrict__ Hcat, const int* __restrict__ off,
    const int* __restrict__ csr, const float* __restrict__ ssrc,
    const float* __restrict__ sdst, const float* __restrict__ bvec,
    float* __restrict__ Gcat, int N) {
    int n = blockIdx.x;
    int lane = threadIdx.x;
    int o0 = off[n], o1 = off[n + 1];
    float sd[4];
#pragma unroll
    for (int h = 0; h < HEADS; ++h) sd[h] = sdst[h * N + n];
    // pass 1: segment max per head (lane-parallel over edges)
    float m[4] = {-1e30f, -1e30f, -1e30f, -1e30f};
    for (int base = o0; base < o1; base += 64) {
        int i = base + lane;
        if (i < o1) {
            int s = csr[i];
#pragma unroll
            for (int h = 0; h < HEADS; ++h) {
                float e = ssrc[h * N + s] + sd[h];
                e = e >= 0.f ? e : 0.2f * e;
                m[h] = fmaxf(m[h], e);
            }
        }
    }
#pragma unroll
    for (int h = 0; h < HEADS; ++h)
        for (int o = 32; o; o >>= 1) m[h] = fmaxf(m[h], __shfl_xor(m[h], o));
    // pass 2: exp-sum + weighted gather (edge-sequential, lanes over columns)
    float denom[4] = {0.f, 0.f, 0.f, 0.f};
    float acc[8] = {0.f, 0.f, 0.f, 0.f, 0.f, 0.f, 0.f, 0.f};
    for (int i = o0; i < o1; ++i) {
        int s = csr[i];
        float ew[4];
#pragma unroll
        for (int h = 0; h < HEADS; ++h) {
            float e = ssrc[h * N + s] + sd[h];
            e = e >= 0.f ? e : 0.2f * e;
            ew[h] = __expf(e - m[h]);
            denom[h] += ew[h];
        }
        const float* Hr = Hcat + (size_t)s * HCAT;
#pragma unroll
        for (int k = 0; k < 8; ++k) acc[k] += ew[k >> 1] * Hr[k * 64 + lane];
    }
#pragma unroll
    for (int k = 0; k < 8; ++k) {
        int h = k >> 1;
        int j = (k * 64 + lane) & 127;
        Gcat[(size_t)n * HCAT + k * 64 + lane] = acc[k] / denom[h] + bvec[h * FDIM + j];
    }
}

// ---------------------------------------------------------------------------
static void run_layer(const float* X, const float* W, const float* asrc,
                      const float* adst, const float* bv, const float* linW,
                      const float* linb, float* Hcat, float* Gcat, float* ssrc,
                      float* sdst, const int* off, const int* csr, float* Yout,
                      int N, hipStream_t s) {
    int mblocks = (N + 63) / 64;
    k_gemm64<0, 1><<<dim3(mblocks, 8), 256, 0, s>>>(X, FDIM, W, nullptr, Hcat, HCAT, N, FDIM);
    k_scores<<<N, 256, 0, s>>>(Hcat, asrc, adst, ssrc, sdst, N);
    k_aggregate<<<N, 64, 0, s>>>(Hcat, off, csr, ssrc, sdst, bv, Gcat, N);
    k_gemm64<1, 0><<<dim3(mblocks, 2), 256, 0, s>>>(Gcat, HCAT, linW, linb, Yout, FDIM, N, HCAT);
}

extern "C" void kernel_launch(void* const* d_in, const int* in_sizes, int n_in,
                              void* d_out, int out_size, void* d_ws, size_t ws_size,
                              hipStream_t stream) {
    const float* x = (const float*)d_in[0];
    const void* ei = d_in[1];
    const float* encW = (const float*)d_in[2];
    const float* enc_asrc = (const float*)d_in[3];
    const float* enc_adst = (const float*)d_in[4];
    const float* enc_b = (const float*)d_in[5];
    const float* enc_linW = (const float*)d_in[6];
    const float* enc_linb = (const float*)d_in[7];
    const float* decW = (const float*)d_in[8];
    const float* dec_asrc = (const float*)d_in[9];
    const float* dec_adst = (const float*)d_in[10];
    const float* dec_b = (const float*)d_in[11];
    const float* dec_linW = (const float*)d_in[12];
    const float* dec_linb = (const float*)d_in[13];

    int N = in_sizes[0] / FDIM;
    int E = in_sizes[1] / 2;
    int Etot = E + N;

    // workspace carve (256B aligned)
    char* w = (char*)d_ws;
    size_t o = 0;
    auto alloc = [&](size_t bytes) -> char* {
        char* p = w + o;
        o += (bytes + 255) & ~(size_t)255;
        return p;
    };
    int* flag = (int*)alloc(4);
    int* deg = (int*)alloc((size_t)N * 4);
    int* off = (int*)alloc((size_t)(N + 1) * 4);
    int* cur = (int*)alloc((size_t)N * 4);
    int* csr = (int*)alloc((size_t)Etot * 4);
    float* ssrc = (float*)alloc((size_t)HEADS * N * 4);
    float* sdst = (float*)alloc((size_t)HEADS * N * 4);
    float* Hcat = (float*)alloc((size_t)N * HCAT * 4);
    float* Gcat = (float*)alloc((size_t)N * HCAT * 4);
    float* X2 = (float*)alloc((size_t)N * FDIM * 4);
    (void)ws_size;

    // CSR build (by destination), once per call
    k_detect<<<1, 64, 0, stream>>>(ei, E, N, flag);
    k_zero_i32<<<(N + 255) / 256, 256, 0, stream>>>(deg, N);
    k_count<<<(Etot + 255) / 256, 256, 0, stream>>>(ei, flag, E, N, deg);
    k_scan<<<1, 1024, 0, stream>>>(deg, off, cur, N);
    k_fill<<<(Etot + 255) / 256, 256, 0, stream>>>(ei, flag, E, N, cur, csr);

    // encoder
    run_layer(x, encW, enc_asrc, enc_adst, enc_b, enc_linW, enc_linb,
              Hcat, Gcat, ssrc, sdst, off, csr, X2, N, stream);
    // decoder
    run_layer(X2, decW, dec_asrc, dec_adst, dec_b, dec_linW, dec_linb,
              Hcat, Gcat, ssrc, sdst, off, csr, (float*)d_out, N, stream);
}

// Round 3
// 972.089 us; speedup vs baseline: 1.2388x; 1.2388x over previous
//
#include <hip/hip_runtime.h>
#include <cstdint>
#include <cstddef>

// ---------------------------------------------------------------------------
// GraphAutoencoder: 2 layers of [4-head GATConv(128->128) -> concat -> Linear(512->128) -> ReLU]
// N=50000 nodes, E=800000 edges (+N self-loops). All fp32.
// GEMMs via split-bf16 MFMA (hi/lo decomposition, 3 products, fp32 accumulate).
// ---------------------------------------------------------------------------

#define FDIM   128
#define HEADS  4
#define HCAT   512   // HEADS * FDIM

typedef __attribute__((ext_vector_type(4))) float f32x4;
typedef __attribute__((ext_vector_type(8))) short bf16x8;

__device__ __forceinline__ unsigned short f2b_rne(float f) {
    unsigned u = __float_as_uint(f);
    unsigned r = (u + 0x7FFFu + ((u >> 16) & 1u)) >> 16;
    return (unsigned short)r;
}
__device__ __forceinline__ float b2f(unsigned short h) {
    return __uint_as_float(((unsigned)h) << 16);
}

// ---------------- edge dtype detection (int64 vs int32) ---------------------
__global__ void k_detect(const void* ei, int E, int N, int* flag) {
    if (threadIdx.x == 0 && blockIdx.x == 0) {
        const long long* p = (const long long*)ei;
        int bad = 0;
        int n = E < 64 ? E : 64;
        for (int i = 0; i < n; ++i) {
            long long v = p[i];
            if (v < 0 || v >= (long long)N) bad = 1;
        }
        *flag = bad;  // 1 => buffer is int32, 0 => int64
    }
}

__device__ __forceinline__ int edge_at(const void* ei, int is32, long long pos) {
    return is32 ? ((const int*)ei)[pos] : (int)(((const long long*)ei)[pos]);
}

__global__ void k_zero_i32(int* p, int n) {
    int i = blockIdx.x * blockDim.x + threadIdx.x;
    if (i < n) p[i] = 0;
}

__global__ void k_count(const void* ei, const int* flag, int E, int N, int* deg) {
    int e = blockIdx.x * blockDim.x + threadIdx.x;
    int Etot = E + N;
    if (e >= Etot) return;
    int is32 = *flag;
    int dst = (e < E) ? edge_at(ei, is32, (long long)E + e) : (e - E);
    atomicAdd(&deg[dst], 1);
}

// single-block exclusive scan over deg[N] -> off[N+1]; cur[] = copy of off[0..N)
__global__ __launch_bounds__(1024) void k_scan(const int* deg, int* off, int* cur, int N) {
    __shared__ int ssum[1024];
    int tid = threadIdx.x;
    int chunk = (N + 1023) / 1024;
    int start = tid * chunk;
    int end = start + chunk;
    if (start > N) start = N;
    if (end > N) end = N;
    int s = 0;
    for (int i = start; i < end; ++i) s += deg[i];
    ssum[tid] = s;
    __syncthreads();
    for (int o = 1; o < 1024; o <<= 1) {
        int v = 0;
        if (tid >= o) v = ssum[tid - o];
        __syncthreads();
        ssum[tid] += v;
        __syncthreads();
    }
    int base = (tid == 0) ? 0 : ssum[tid - 1];
    for (int i = start; i < end; ++i) {
        off[i] = base;
        cur[i] = base;
        base += deg[i];
    }
    if (tid == 1023) off[N] = ssum[1023];
}

__global__ void k_fill(const void* ei, const int* flag, int E, int N, int* cur, int* csr) {
    int e = blockIdx.x * blockDim.x + threadIdx.x;
    int Etot = E + N;
    if (e >= Etot) return;
    int is32 = *flag;
    int src, dst;
    if (e < E) {
        src = edge_at(ei, is32, e);
        dst = edge_at(ei, is32, (long long)E + e);
    } else {
        src = e - E;
        dst = e - E;
    }
    int pos = atomicAdd(&cur[dst], 1);
    csr[pos] = src;
}

// ---------------- split-bf16 MFMA GEMM ----------------
// C[M x (ncolblk*128)] = A[M x K] * B, B is [ncolblk][K][128] row-major blocks.
// Block tile 128x128 (4 waves, 2x2 of 64x64 wave tiles). BK=32.
// A (fp32) and B (fp32) are split into hi/lo bf16 in LDS; 3 MFMA per product.
template <int BIAS_RELU>
__global__ __launch_bounds__(256) void k_gemm_mfma(
    const float* __restrict__ A, int lda,
    const float* __restrict__ B,
    const float* __restrict__ bias,
    float* __restrict__ C, int ldc, int M, int K)
{
    __shared__ alignas(16) char smem[32768];
    const int AHI = 0, ALO = 8192, BHI = 16384, BLO = 24576;
    int tid = threadIdx.x;
    int bm0 = blockIdx.x * 128;
    int yb = blockIdx.y;
    const float* Bp = B + (size_t)yb * K * 128;

    int wid = tid >> 6, lane = tid & 63;
    int wr = wid >> 1, wc = wid & 1;
    int fr = lane & 15, g = lane >> 4;

    f32x4 acc[4][4] = {};

    // staging indices
    int arow = tid >> 1, ahalf = tid & 1;           // A: 2 threads/row, 16 k each
    bool ain = (bm0 + arow) < M;
    const float* aptr = A + (size_t)(bm0 + arow) * lda + ahalf * 16;
    int bcol = tid & 127, bhalf = tid >> 7;         // B: 2 threads/col, 16 k each
    const float* bptr = Bp + (size_t)(bhalf * 16) * 128 + bcol;

    int abase = arow * 64 + ahalf * 32;
    int asw = (arow & 7) << 4;
    int bbase = bcol * 64 + bhalf * 32;
    int bsw = (bcol & 7) << 4;

    for (int k0 = 0; k0 < K; k0 += 32) {
        // ---- stage A tile (128 rows x 32 k) ----
        float av[16];
        if (ain) {
#pragma unroll
            for (int i = 0; i < 4; ++i)
                *(float4*)&av[i * 4] = *(const float4*)(aptr + k0 + i * 4);
        } else {
#pragma unroll
            for (int i = 0; i < 16; ++i) av[i] = 0.f;
        }
        unsigned short ahi[16], alo[16];
#pragma unroll
        for (int i = 0; i < 16; ++i) {
            unsigned short h = f2b_rne(av[i]);
            ahi[i] = h;
            alo[i] = f2b_rne(av[i] - b2f(h));
        }
        *(bf16x8*)(smem + AHI + ((abase +  0) ^ asw)) = *(bf16x8*)&ahi[0];
        *(bf16x8*)(smem + AHI + ((abase + 16) ^ asw)) = *(bf16x8*)&ahi[8];
        *(bf16x8*)(smem + ALO + ((abase +  0) ^ asw)) = *(bf16x8*)&alo[0];
        *(bf16x8*)(smem + ALO + ((abase + 16) ^ asw)) = *(bf16x8*)&alo[8];

        // ---- stage B tile (32 k x 128 cols), transposed to [col][k] ----
        float bv[16];
#pragma unroll
        for (int i = 0; i < 16; ++i)
            bv[i] = bptr[(size_t)k0 * 128 + (size_t)i * 128];
        unsigned short bhi[16], blo[16];
#pragma unroll
        for (int i = 0; i < 16; ++i) {
            unsigned short h = f2b_rne(bv[i]);
            bhi[i] = h;
            blo[i] = f2b_rne(bv[i] - b2f(h));
        }
        *(bf16x8*)(smem + BHI + ((bbase +  0) ^ bsw)) = *(bf16x8*)&bhi[0];
        *(bf16x8*)(smem + BHI + ((bbase + 16) ^ bsw)) = *(bf16x8*)&bhi[8];
        *(bf16x8*)(smem + BLO + ((bbase +  0) ^ bsw)) = *(bf16x8*)&blo[0];
        *(bf16x8*)(smem + BLO + ((bbase + 16) ^ bsw)) = *(bf16x8*)&blo[8];

        __syncthreads();

        // ---- fragment loads ----
        bf16x8 ah[4], al[4], bh[4], bl[4];
#pragma unroll
        for (int mi = 0; mi < 4; ++mi) {
            int r = wr * 64 + mi * 16 + fr;
            int off = (r * 64 + g * 16) ^ ((r & 7) << 4);
            ah[mi] = *(bf16x8*)(smem + AHI + off);
            al[mi] = *(bf16x8*)(smem + ALO + off);
        }
#pragma unroll
        for (int nj = 0; nj < 4; ++nj) {
            int c = wc * 64 + nj * 16 + fr;
            int off = (c * 64 + g * 16) ^ ((c & 7) << 4);
            bh[nj] = *(bf16x8*)(smem + BHI + off);
            bl[nj] = *(bf16x8*)(smem + BLO + off);
        }

        // ---- 48 MFMA: hi*hi + hi*lo + lo*hi ----
#pragma unroll
        for (int mi = 0; mi < 4; ++mi)
#pragma unroll
            for (int nj = 0; nj < 4; ++nj) {
                acc[mi][nj] = __builtin_amdgcn_mfma_f32_16x16x32_bf16(ah[mi], bh[nj], acc[mi][nj], 0, 0, 0);
                acc[mi][nj] = __builtin_amdgcn_mfma_f32_16x16x32_bf16(ah[mi], bl[nj], acc[mi][nj], 0, 0, 0);
                acc[mi][nj] = __builtin_amdgcn_mfma_f32_16x16x32_bf16(al[mi], bh[nj], acc[mi][nj], 0, 0, 0);
            }
        __syncthreads();
    }

    // ---- epilogue ----
#pragma unroll
    for (int mi = 0; mi < 4; ++mi) {
#pragma unroll
        for (int q = 0; q < 4; ++q) {
            int r = bm0 + wr * 64 + mi * 16 + g * 4 + q;
            if (r >= M) continue;
#pragma unroll
            for (int nj = 0; nj < 4; ++nj) {
                int clocal = wc * 64 + nj * 16 + fr;
                float v = acc[mi][nj][q];
                if (BIAS_RELU) {
                    v += bias[clocal];
                    v = fmaxf(v, 0.f);
                }
                C[(size_t)r * ldc + yb * 128 + clocal] = v;
            }
        }
    }
}

// ---------------- attention scores: ssrc/sdst[h][n] = Hcat[n,h*128:].a ------
__global__ __launch_bounds__(256) void k_scores(
    const float* __restrict__ Hcat, const float* __restrict__ asrc,
    const float* __restrict__ adst, float* __restrict__ ssrc,
    float* __restrict__ sdst, int N) {
    int n = blockIdx.x;
    int h = (threadIdx.x >> 6) & 3;
    int lane = threadIdx.x & 63;
    if (n >= N) return;
    const float* Hr = Hcat + (size_t)n * HCAT + h * FDIM;
    float a0 = Hr[lane], a1 = Hr[64 + lane];
    float s1 = a0 * asrc[h * FDIM + lane] + a1 * asrc[h * FDIM + 64 + lane];
    float s2 = a0 * adst[h * FDIM + lane] + a1 * adst[h * FDIM + 64 + lane];
    for (int o = 32; o; o >>= 1) {
        s1 += __shfl_xor(s1, o);
        s2 += __shfl_xor(s2, o);
    }
    if (lane == 0) {
        ssrc[h * N + n] = s1;
        sdst[h * N + n] = s2;
    }
}

// ---------------- per-dst segment softmax + aggregate, 1 wave/node ----------
__global__ __launch_bounds__(64) void k_aggregate(
    const float* __restrict__ Hcat, const int* __restrict__ off,
    const int* __restrict__ csr, const float* __restrict__ ssrc,
    const float* __restrict__ sdst, const float* __restrict__ bvec,
    float* __restrict__ Gcat, int N) {
    int n = blockIdx.x;
    int lane = threadIdx.x;
    int o0 = off[n], o1 = off[n + 1];
    float sd[4];
#pragma unroll
    for (int h = 0; h < HEADS; ++h) sd[h] = sdst[h * N + n];
    // pass 1: segment max per head (lane-parallel over edges)
    float m[4] = {-1e30f, -1e30f, -1e30f, -1e30f};
    for (int base = o0; base < o1; base += 64) {
        int i = base + lane;
        if (i < o1) {
            int s = csr[i];
#pragma unroll
            for (int h = 0; h < HEADS; ++h) {
                float e = ssrc[h * N + s] + sd[h];
                e = e >= 0.f ? e : 0.2f * e;
                m[h] = fmaxf(m[h], e);
            }
        }
    }
#pragma unroll
    for (int h = 0; h < HEADS; ++h)
        for (int o = 32; o; o >>= 1) m[h] = fmaxf(m[h], __shfl_xor(m[h], o));
    // pass 2: exp-sum + weighted gather (edge-sequential, lanes over columns)
    float denom[4] = {0.f, 0.f, 0.f, 0.f};
    float acc[8] = {0.f, 0.f, 0.f, 0.f, 0.f, 0.f, 0.f, 0.f};
    for (int i = o0; i < o1; ++i) {
        int s = csr[i];
        float ew[4];
#pragma unroll
        for (int h = 0; h < HEADS; ++h) {
            float e = ssrc[h * N + s] + sd[h];
            e = e >= 0.f ? e : 0.2f * e;
            ew[h] = __expf(e - m[h]);
            denom[h] += ew[h];
        }
        const float* Hr = Hcat + (size_t)s * HCAT;
#pragma unroll
        for (int k = 0; k < 8; ++k) acc[k] += ew[k >> 1] * Hr[k * 64 + lane];
    }
#pragma unroll
    for (int k = 0; k < 8; ++k) {
        int h = k >> 1;
        int j = (k * 64 + lane) & 127;
        Gcat[(size_t)n * HCAT + k * 64 + lane] = acc[k] / denom[h] + bvec[h * FDIM + j];
    }
}

// ---------------------------------------------------------------------------
static void run_layer(const float* X, const float* W, const float* asrc,
                      const float* adst, const float* bv, const float* linW,
                      const float* linb, float* Hcat, float* Gcat, float* ssrc,
                      float* sdst, const int* off, const int* csr, float* Yout,
                      int N, hipStream_t s) {
    int mblocks = (N + 127) / 128;
    // head GEMM: X[N,128] @ W[4][128][128] -> Hcat[N,512]
    k_gemm_mfma<0><<<dim3(mblocks, 4), 256, 0, s>>>(X, FDIM, W, nullptr, Hcat, HCAT, N, FDIM);
    k_scores<<<N, 256, 0, s>>>(Hcat, asrc, adst, ssrc, sdst, N);
    k_aggregate<<<N, 64, 0, s>>>(Hcat, off, csr, ssrc, sdst, bv, Gcat, N);
    // lin GEMM: Gcat[N,512] @ linW[512,128] + b, relu -> Yout[N,128]
    k_gemm_mfma<1><<<dim3(mblocks, 1), 256, 0, s>>>(Gcat, HCAT, linW, linb, Yout, FDIM, N, HCAT);
}

extern "C" void kernel_launch(void* const* d_in, const int* in_sizes, int n_in,
                              void* d_out, int out_size, void* d_ws, size_t ws_size,
                              hipStream_t stream) {
    const float* x = (const float*)d_in[0];
    const void* ei = d_in[1];
    const float* encW = (const float*)d_in[2];
    const float* enc_asrc = (const float*)d_in[3];
    const float* enc_adst = (const float*)d_in[4];
    const float* enc_b = (const float*)d_in[5];
    const float* enc_linW = (const float*)d_in[6];
    const float* enc_linb = (const float*)d_in[7];
    const float* decW = (const float*)d_in[8];
    const float* dec_asrc = (const float*)d_in[9];
    const float* dec_adst = (const float*)d_in[10];
    const float* dec_b = (const float*)d_in[11];
    const float* dec_linW = (const float*)d_in[12];
    const float* dec_linb = (const float*)d_in[13];

    int N = in_sizes[0] / FDIM;
    int E = in_sizes[1] / 2;
    int Etot = E + N;

    // workspace carve (256B aligned)
    char* w = (char*)d_ws;
    size_t o = 0;
    auto alloc = [&](size_t bytes) -> char* {
        char* p = w + o;
        o += (bytes + 255) & ~(size_t)255;
        return p;
    };
    int* flag = (int*)alloc(4);
    int* deg = (int*)alloc((size_t)N * 4);
    int* off = (int*)alloc((size_t)(N + 1) * 4);
    int* cur = (int*)alloc((size_t)N * 4);
    int* csr = (int*)alloc((size_t)Etot * 4);
    float* ssrc = (float*)alloc((size_t)HEADS * N * 4);
    float* sdst = (float*)alloc((size_t)HEADS * N * 4);
    float* Hcat = (float*)alloc((size_t)N * HCAT * 4);
    float* Gcat = (float*)alloc((size_t)N * HCAT * 4);
    float* X2 = (float*)alloc((size_t)N * FDIM * 4);
    (void)ws_size;

    // CSR build (by destination), once per call
    k_detect<<<1, 64, 0, stream>>>(ei, E, N, flag);
    k_zero_i32<<<(N + 255) / 256, 256, 0, stream>>>(deg, N);
    k_count<<<(Etot + 255) / 256, 256, 0, stream>>>(ei, flag, E, N, deg);
    k_scan<<<1, 1024, 0, stream>>>(deg, off, cur, N);
    k_fill<<<(Etot + 255) / 256, 256, 0, stream>>>(ei, flag, E, N, cur, csr);

    // encoder
    run_layer(x, encW, enc_asrc, enc_adst, enc_b, enc_linW, enc_linb,
              Hcat, Gcat, ssrc, sdst, off, csr, X2, N, stream);
    // decoder
    run_layer(X2, decW, dec_asrc, dec_adst, dec_b, dec_linW, dec_linb,
              Hcat, Gcat, ssrc, sdst, off, csr, (float*)d_out, N, stream);
}

// Round 4
// 748.890 us; speedup vs baseline: 1.6080x; 1.2980x over previous
//
#include <hip/hip_runtime.h>
#include <hip/hip_fp16.h>
#include <cstdint>
#include <cstddef>

// ---------------------------------------------------------------------------
// GraphAutoencoder: 2 x [4-head GATConv(128->128) -> concat -> Linear(512->128) -> ReLU]
// N=50000, E=800000 (+N self-loops). fp32 in/out.
// GEMMs: split-bf16 MFMA with PRE-SPLIT operands (hi/lo bf16, 3 products).
// Aggregate: fp16 gather (1KB/row), lane-owns-8-contiguous-columns.
// ---------------------------------------------------------------------------

#define FDIM   128
#define HEADS  4
#define HCAT   512

typedef unsigned short u16;
typedef __attribute__((ext_vector_type(4))) float f32x4;
typedef __attribute__((ext_vector_type(8))) short bf16x8;

__device__ __forceinline__ u16 f2b_rne(float f) {
    unsigned u = __float_as_uint(f);
    unsigned r = (u + 0x7FFFu + ((u >> 16) & 1u)) >> 16;
    return (u16)r;
}
__device__ __forceinline__ float b2f(u16 h) {
    return __uint_as_float(((unsigned)h) << 16);
}

// ---------------- edge dtype detection (int64 vs int32) ---------------------
__global__ void k_detect(const void* ei, int E, int N, int* flag) {
    if (threadIdx.x == 0 && blockIdx.x == 0) {
        const long long* p = (const long long*)ei;
        int bad = 0;
        int n = E < 64 ? E : 64;
        for (int i = 0; i < n; ++i) {
            long long v = p[i];
            if (v < 0 || v >= (long long)N) bad = 1;
        }
        *flag = bad;  // 1 => int32, 0 => int64
    }
}

__device__ __forceinline__ int edge_at(const void* ei, int is32, long long pos) {
    return is32 ? ((const int*)ei)[pos] : (int)(((const long long*)ei)[pos]);
}

__global__ void k_zero_i32(int* p, int n) {
    int i = blockIdx.x * blockDim.x + threadIdx.x;
    if (i < n) p[i] = 0;
}

__global__ void k_count(const void* ei, const int* flag, int E, int N, int* deg) {
    int e = blockIdx.x * blockDim.x + threadIdx.x;
    int Etot = E + N;
    if (e >= Etot) return;
    int is32 = *flag;
    int dst = (e < E) ? edge_at(ei, is32, (long long)E + e) : (e - E);
    atomicAdd(&deg[dst], 1);
}

__global__ __launch_bounds__(1024) void k_scan(const int* deg, int* off, int* cur, int N) {
    __shared__ int ssum[1024];
    int tid = threadIdx.x;
    int chunk = (N + 1023) / 1024;
    int start = tid * chunk;
    int end = start + chunk;
    if (start > N) start = N;
    if (end > N) end = N;
    int s = 0;
    for (int i = start; i < end; ++i) s += deg[i];
    ssum[tid] = s;
    __syncthreads();
    for (int o = 1; o < 1024; o <<= 1) {
        int v = 0;
        if (tid >= o) v = ssum[tid - o];
        __syncthreads();
        ssum[tid] += v;
        __syncthreads();
    }
    int base = (tid == 0) ? 0 : ssum[tid - 1];
    for (int i = start; i < end; ++i) {
        off[i] = base;
        cur[i] = base;
        base += deg[i];
    }
    if (tid == 1023) off[N] = ssum[1023];
}

__global__ void k_fill(const void* ei, const int* flag, int E, int N, int* cur, int* csr) {
    int e = blockIdx.x * blockDim.x + threadIdx.x;
    int Etot = E + N;
    if (e >= Etot) return;
    int is32 = *flag;
    int src, dst;
    if (e < E) {
        src = edge_at(ei, is32, e);
        dst = edge_at(ei, is32, (long long)E + e);
    } else {
        src = e - E;
        dst = e - E;
    }
    int pos = atomicAdd(&cur[dst], 1);
    csr[pos] = src;
}

// ---------------- operand pre-split kernels ---------------------------------
// W [nblk][K][128] fp32 -> Bt hi/lo [nblk][128][K] bf16 (transposed)
__global__ void k_splitw(const float* __restrict__ W, u16* __restrict__ hi,
                         u16* __restrict__ lo, int nblk, int K) {
    int idx = blockIdx.x * blockDim.x + threadIdx.x;
    int total = nblk * K * 128;
    if (idx >= total) return;
    int blk = idx / (K * 128);
    int rem = idx - blk * K * 128;
    int k = rem >> 7, col = rem & 127;
    float v = W[idx];
    u16 h = f2b_rne(v);
    size_t o = (size_t)blk * 128 * K + (size_t)col * K + k;
    hi[o] = h;
    lo[o] = f2b_rne(v - b2f(h));
}

__global__ void k_splitx(const float* __restrict__ X, u16* __restrict__ hi,
                         u16* __restrict__ lo, int n) {
    int i = blockIdx.x * blockDim.x + threadIdx.x;
    if (i >= n) return;
    float v = X[i];
    u16 h = f2b_rne(v);
    hi[i] = h;
    lo[i] = f2b_rne(v - b2f(h));
}

// ---------------- split-bf16 MFMA GEMM (pre-split operands) -----------------
// C[M x ncolblk*128] = A[M x K] * B. A: hi/lo bf16 [M][lda]. Bt: hi/lo bf16
// [ncolblk][128][K] (col-major per block). 128x128 block tile, 4 waves, BK=32.
// MODE 0: write C fp32 (ldc, col yb*128+c) + Cb1 = fp16(C) (head GEMM)
// MODE 1: bias+relu, write Cb1/Cb2 = bf16 hi/lo [M][128] (encoder lin GEMM)
// MODE 2: bias+relu, write C fp32 [M][128] (decoder lin GEMM -> d_out)
template <int MODE>
__global__ __launch_bounds__(256) void k_gemm_bf(
    const u16* __restrict__ Ahi, const u16* __restrict__ Alo, int lda,
    const u16* __restrict__ Bthi, const u16* __restrict__ Btlo,
    const float* __restrict__ bias,
    float* __restrict__ C, u16* __restrict__ Cb1, u16* __restrict__ Cb2,
    int ldc, int M, int K)
{
    __shared__ alignas(16) char smem[32768];
    const int AHI = 0, ALO = 8192, BHI = 16384, BLO = 24576;
    int tid = threadIdx.x;
    int bm0 = blockIdx.x * 128;
    int yb = blockIdx.y;

    int wid = tid >> 6, lane = tid & 63;
    int wr = wid >> 1, wc = wid & 1;
    int fr = lane & 15, g = lane >> 4;

    f32x4 acc[4][4] = {};

    int arow = tid >> 1, ahalf = tid & 1;
    bool ain = (bm0 + arow) < M;
    const u16* aph = Ahi + (size_t)(bm0 + arow) * lda + ahalf * 16;
    const u16* apl = Alo + (size_t)(bm0 + arow) * lda + ahalf * 16;
    int bcol = tid & 127, bhalf = tid >> 7;
    const u16* bph = Bthi + (size_t)yb * 128 * K + (size_t)bcol * K + bhalf * 16;
    const u16* bpl = Btlo + (size_t)yb * 128 * K + (size_t)bcol * K + bhalf * 16;

    int abase = arow * 64 + ahalf * 32;
    int asw = (arow & 7) << 4;
    int bbase = bcol * 64 + bhalf * 32;
    int bsw = (bcol & 7) << 4;

    for (int k0 = 0; k0 < K; k0 += 32) {
        bf16x8 va0, va1, vl0, vl1;
        if (ain) {
            va0 = *(const bf16x8*)(aph + k0);
            va1 = *(const bf16x8*)(aph + k0 + 8);
            vl0 = *(const bf16x8*)(apl + k0);
            vl1 = *(const bf16x8*)(apl + k0 + 8);
        } else {
            va0 = (bf16x8)0; va1 = (bf16x8)0; vl0 = (bf16x8)0; vl1 = (bf16x8)0;
        }
        bf16x8 vb0 = *(const bf16x8*)(bph + k0);
        bf16x8 vb1 = *(const bf16x8*)(bph + k0 + 8);
        bf16x8 vm0 = *(const bf16x8*)(bpl + k0);
        bf16x8 vm1 = *(const bf16x8*)(bpl + k0 + 8);

        *(bf16x8*)(smem + AHI + ((abase +  0) ^ asw)) = va0;
        *(bf16x8*)(smem + AHI + ((abase + 16) ^ asw)) = va1;
        *(bf16x8*)(smem + ALO + ((abase +  0) ^ asw)) = vl0;
        *(bf16x8*)(smem + ALO + ((abase + 16) ^ asw)) = vl1;
        *(bf16x8*)(smem + BHI + ((bbase +  0) ^ bsw)) = vb0;
        *(bf16x8*)(smem + BHI + ((bbase + 16) ^ bsw)) = vb1;
        *(bf16x8*)(smem + BLO + ((bbase +  0) ^ bsw)) = vm0;
        *(bf16x8*)(smem + BLO + ((bbase + 16) ^ bsw)) = vm1;

        __syncthreads();

        bf16x8 ah[4], al[4], bh[4], bl[4];
#pragma unroll
        for (int mi = 0; mi < 4; ++mi) {
            int r = wr * 64 + mi * 16 + fr;
            int off = (r * 64 + g * 16) ^ ((r & 7) << 4);
            ah[mi] = *(bf16x8*)(smem + AHI + off);
            al[mi] = *(bf16x8*)(smem + ALO + off);
        }
#pragma unroll
        for (int nj = 0; nj < 4; ++nj) {
            int c = wc * 64 + nj * 16 + fr;
            int off = (c * 64 + g * 16) ^ ((c & 7) << 4);
            bh[nj] = *(bf16x8*)(smem + BHI + off);
            bl[nj] = *(bf16x8*)(smem + BLO + off);
        }

#pragma unroll
        for (int mi = 0; mi < 4; ++mi)
#pragma unroll
            for (int nj = 0; nj < 4; ++nj) {
                acc[mi][nj] = __builtin_amdgcn_mfma_f32_16x16x32_bf16(ah[mi], bh[nj], acc[mi][nj], 0, 0, 0);
                acc[mi][nj] = __builtin_amdgcn_mfma_f32_16x16x32_bf16(ah[mi], bl[nj], acc[mi][nj], 0, 0, 0);
                acc[mi][nj] = __builtin_amdgcn_mfma_f32_16x16x32_bf16(al[mi], bh[nj], acc[mi][nj], 0, 0, 0);
            }
        __syncthreads();
    }

#pragma unroll
    for (int mi = 0; mi < 4; ++mi) {
#pragma unroll
        for (int q = 0; q < 4; ++q) {
            int r = bm0 + wr * 64 + mi * 16 + g * 4 + q;
            if (r >= M) continue;
#pragma unroll
            for (int nj = 0; nj < 4; ++nj) {
                int clocal = wc * 64 + nj * 16 + fr;
                float v = acc[mi][nj][q];
                if (MODE == 0) {
                    size_t idx = (size_t)r * ldc + yb * 128 + clocal;
                    C[idx] = v;
                    __half hv = __float2half(v);
                    Cb1[idx] = *(u16*)&hv;
                } else if (MODE == 1) {
                    v += bias[clocal];
                    v = fmaxf(v, 0.f);
                    size_t idx = (size_t)r * ldc + clocal;
                    u16 h = f2b_rne(v);
                    Cb1[idx] = h;
                    Cb2[idx] = f2b_rne(v - b2f(h));
                } else {
                    v += bias[clocal];
                    v = fmaxf(v, 0.f);
                    C[(size_t)r * ldc + clocal] = v;
                }
            }
        }
    }
}

// ---------------- attention scores ------------------------------------------
__global__ __launch_bounds__(256) void k_scores(
    const float* __restrict__ Hcat, const float* __restrict__ asrc,
    const float* __restrict__ adst, float* __restrict__ ssrc,
    float* __restrict__ sdst, int N) {
    int n = blockIdx.x;
    int h = (threadIdx.x >> 6) & 3;
    int lane = threadIdx.x & 63;
    if (n >= N) return;
    const float* Hr = Hcat + (size_t)n * HCAT + h * FDIM;
    float a0 = Hr[lane], a1 = Hr[64 + lane];
    float s1 = a0 * asrc[h * FDIM + lane] + a1 * asrc[h * FDIM + 64 + lane];
    float s2 = a0 * adst[h * FDIM + lane] + a1 * adst[h * FDIM + 64 + lane];
    for (int o = 32; o; o >>= 1) {
        s1 += __shfl_xor(s1, o);
        s2 += __shfl_xor(s2, o);
    }
    if (lane == 0) {
        ssrc[h * N + n] = s1;
        sdst[h * N + n] = s2;
    }
}

// ---------------- segment softmax + fp16 gather aggregate -------------------
// 1 wave/node. Lane l owns columns [8l, 8l+8) (all in head l>>4).
// Output written as bf16 hi/lo split (feeds lin GEMM directly).
__global__ __launch_bounds__(64) void k_aggregate(
    const u16* __restrict__ Hb, const int* __restrict__ off,
    const int* __restrict__ csr, const float* __restrict__ ssrc,
    const float* __restrict__ sdst, const float* __restrict__ bvec,
    u16* __restrict__ Ghi, u16* __restrict__ Glo, int N) {
    int n = blockIdx.x;
    int lane = threadIdx.x;
    int o0 = off[n], o1 = off[n + 1];
    int h = lane >> 4;
    int col0 = lane * 8;
    float sd4[4];
#pragma unroll
    for (int hh = 0; hh < HEADS; ++hh) sd4[hh] = sdst[hh * N + n];
    // pass 1: per-head segment max (lane-parallel over edges)
    float m[4] = {-1e30f, -1e30f, -1e30f, -1e30f};
    for (int base = o0; base < o1; base += 64) {
        int i = base + lane;
        if (i < o1) {
            int s = csr[i];
#pragma unroll
            for (int hh = 0; hh < HEADS; ++hh) {
                float e = ssrc[hh * N + s] + sd4[hh];
                e = e >= 0.f ? e : 0.2f * e;
                m[hh] = fmaxf(m[hh], e);
            }
        }
    }
#pragma unroll
    for (int hh = 0; hh < HEADS; ++hh)
        for (int o = 32; o; o >>= 1) m[hh] = fmaxf(m[hh], __shfl_xor(m[hh], o));
    float mh = m[h], sdh = sd4[h];
    // pass 2: exp-sum + fp16 gather (edge-sequential; lane covers its 8 cols)
    float denom = 0.f;
    float acc[8] = {0.f, 0.f, 0.f, 0.f, 0.f, 0.f, 0.f, 0.f};
    const float* ssrc_h = ssrc + (size_t)h * N;
    for (int i = o0; i < o1; ++i) {
        int s = csr[i];
        float e = ssrc_h[s] + sdh;
        e = e >= 0.f ? e : 0.2f * e;
        float ew = __expf(e - mh);
        denom += ew;
        uint4 hv = *(const uint4*)&Hb[(size_t)s * HCAT + col0];
        const __half2* hp = (const __half2*)&hv;
#pragma unroll
        for (int j = 0; j < 4; ++j) {
            float2 f = __half22float2(hp[j]);
            acc[2 * j]     += ew * f.x;
            acc[2 * j + 1] += ew * f.y;
        }
    }
    u16 hs[8], ls[8];
#pragma unroll
    for (int k = 0; k < 8; ++k) {
        int col = col0 + k;
        float v = acc[k] / denom + bvec[h * FDIM + (col & 127)];
        u16 hbits = f2b_rne(v);
        hs[k] = hbits;
        ls[k] = f2b_rne(v - b2f(hbits));
    }
    *(uint4*)&Ghi[(size_t)n * HCAT + col0] = *(uint4*)hs;
    *(uint4*)&Glo[(size_t)n * HCAT + col0] = *(uint4*)ls;
}

// ---------------------------------------------------------------------------
extern "C" void kernel_launch(void* const* d_in, const int* in_sizes, int n_in,
                              void* d_out, int out_size, void* d_ws, size_t ws_size,
                              hipStream_t stream) {
    const float* x = (const float*)d_in[0];
    const void* ei = d_in[1];
    const float* encW = (const float*)d_in[2];
    const float* enc_asrc = (const float*)d_in[3];
    const float* enc_adst = (const float*)d_in[4];
    const float* enc_b = (const float*)d_in[5];
    const float* enc_linW = (const float*)d_in[6];
    const float* enc_linb = (const float*)d_in[7];
    const float* decW = (const float*)d_in[8];
    const float* dec_asrc = (const float*)d_in[9];
    const float* dec_adst = (const float*)d_in[10];
    const float* dec_b = (const float*)d_in[11];
    const float* dec_linW = (const float*)d_in[12];
    const float* dec_linb = (const float*)d_in[13];

    int N = in_sizes[0] / FDIM;
    int E = in_sizes[1] / 2;
    int Etot = E + N;

    char* w = (char*)d_ws;
    size_t o = 0;
    auto alloc = [&](size_t bytes) -> char* {
        char* p = w + o;
        o += (bytes + 255) & ~(size_t)255;
        return p;
    };
    int* flag = (int*)alloc(4);
    int* deg = (int*)alloc((size_t)N * 4);
    int* off = (int*)alloc((size_t)(N + 1) * 4);
    int* cur = (int*)alloc((size_t)N * 4);
    int* csr = (int*)alloc((size_t)Etot * 4);
    float* ssrc = (float*)alloc((size_t)HEADS * N * 4);
    float* sdst = (float*)alloc((size_t)HEADS * N * 4);
    // Hcat fp32 region; Ghi/Glo alias it (Hcat dead once aggregate runs)
    float* Hcat = (float*)alloc((size_t)N * HCAT * 4);
    u16* Ghi = (u16*)Hcat;
    u16* Glo = Ghi + (size_t)N * HCAT;
    u16* Hb = (u16*)alloc((size_t)N * HCAT * 2);
    u16* xhi = (u16*)alloc((size_t)N * FDIM * 2);
    u16* xlo = (u16*)alloc((size_t)N * FDIM * 2);
    u16* X2hi = (u16*)alloc((size_t)N * FDIM * 2);
    u16* X2lo = (u16*)alloc((size_t)N * FDIM * 2);
    u16* encWt_h = (u16*)alloc((size_t)HEADS * FDIM * FDIM * 2);
    u16* encWt_l = (u16*)alloc((size_t)HEADS * FDIM * FDIM * 2);
    u16* linWt_h = (u16*)alloc((size_t)HCAT * FDIM * 2);
    u16* linWt_l = (u16*)alloc((size_t)HCAT * FDIM * 2);
    u16* decWt_h = (u16*)alloc((size_t)HEADS * FDIM * FDIM * 2);
    u16* decWt_l = (u16*)alloc((size_t)HEADS * FDIM * FDIM * 2);
    u16* dlinWt_h = (u16*)alloc((size_t)HCAT * FDIM * 2);
    u16* dlinWt_l = (u16*)alloc((size_t)HCAT * FDIM * 2);
    (void)ws_size;

    // CSR build
    k_detect<<<1, 64, 0, stream>>>(ei, E, N, flag);
    k_zero_i32<<<(N + 255) / 256, 256, 0, stream>>>(deg, N);
    k_count<<<(Etot + 255) / 256, 256, 0, stream>>>(ei, flag, E, N, deg);
    k_scan<<<1, 1024, 0, stream>>>(deg, off, cur, N);
    k_fill<<<(Etot + 255) / 256, 256, 0, stream>>>(ei, flag, E, N, cur, csr);

    // operand pre-splits
    int wtot = HEADS * FDIM * FDIM;
    k_splitw<<<(wtot + 255) / 256, 256, 0, stream>>>(encW, encWt_h, encWt_l, HEADS, FDIM);
    k_splitw<<<(wtot + 255) / 256, 256, 0, stream>>>(enc_linW, linWt_h, linWt_l, 1, HCAT);
    k_splitw<<<(wtot + 255) / 256, 256, 0, stream>>>(decW, decWt_h, decWt_l, HEADS, FDIM);
    k_splitw<<<(wtot + 255) / 256, 256, 0, stream>>>(dec_linW, dlinWt_h, dlinWt_l, 1, HCAT);
    k_splitx<<<(N * FDIM + 255) / 256, 256, 0, stream>>>(x, xhi, xlo, N * FDIM);

    int mblocks = (N + 127) / 128;

    // ---- encoder ----
    k_gemm_bf<0><<<dim3(mblocks, 4), 256, 0, stream>>>(
        xhi, xlo, FDIM, encWt_h, encWt_l, nullptr, Hcat, Hb, nullptr, HCAT, N, FDIM);
    k_scores<<<N, 256, 0, stream>>>(Hcat, enc_asrc, enc_adst, ssrc, sdst, N);
    k_aggregate<<<N, 64, 0, stream>>>(Hb, off, csr, ssrc, sdst, enc_b, Ghi, Glo, N);
    k_gemm_bf<1><<<dim3(mblocks, 1), 256, 0, stream>>>(
        Ghi, Glo, HCAT, linWt_h, linWt_l, enc_linb, nullptr, X2hi, X2lo, FDIM, N, HCAT);

    // ---- decoder ----
    k_gemm_bf<0><<<dim3(mblocks, 4), 256, 0, stream>>>(
        X2hi, X2lo, FDIM, decWt_h, decWt_l, nullptr, Hcat, Hb, nullptr, HCAT, N, FDIM);
    k_scores<<<N, 256, 0, stream>>>(Hcat, dec_asrc, dec_adst, ssrc, sdst, N);
    k_aggregate<<<N, 64, 0, stream>>>(Hb, off, csr, ssrc, sdst, dec_b, Ghi, Glo, N);
    k_gemm_bf<2><<<dim3(mblocks, 1), 256, 0, stream>>>(
        Ghi, Glo, HCAT, dlinWt_h, dlinWt_l, dec_linb, (float*)d_out, nullptr, nullptr, FDIM, N, HCAT);
}

// Round 5
// 594.312 us; speedup vs baseline: 2.0263x; 1.2601x over previous
//
#include <hip/hip_runtime.h>
#include <hip/hip_fp16.h>
#include <cstdint>
#include <cstddef>

// ---------------------------------------------------------------------------
// GraphAutoencoder: 2 x [4-head GATConv(128->128) -> concat -> Linear(512->128) -> ReLU]
// N=50000, E=800000 (+N self-loops). fp32 in/out.
// GEMMs: split-bf16 MFMA, pre-split operands. Scores fused into head-GEMM
// epilogue (no fp32 Hcat). Aggregate: fp16 gather, no max pass (scores O(1)).
// ---------------------------------------------------------------------------

#define FDIM   128
#define HEADS  4
#define HCAT   512

typedef unsigned short u16;
typedef __attribute__((ext_vector_type(4))) float f32x4;
typedef __attribute__((ext_vector_type(8))) short bf16x8;

__device__ __forceinline__ u16 f2b_rne(float f) {
    unsigned u = __float_as_uint(f);
    unsigned r = (u + 0x7FFFu + ((u >> 16) & 1u)) >> 16;
    return (u16)r;
}
__device__ __forceinline__ float b2f(u16 h) {
    return __uint_as_float(((unsigned)h) << 16);
}

// ---------------- edge dtype detection (int64 vs int32) ---------------------
__global__ void k_detect(const void* ei, int E, int N, int* flag) {
    if (threadIdx.x == 0 && blockIdx.x == 0) {
        const long long* p = (const long long*)ei;
        int bad = 0;
        int n = E < 64 ? E : 64;
        for (int i = 0; i < n; ++i) {
            long long v = p[i];
            if (v < 0 || v >= (long long)N) bad = 1;
        }
        *flag = bad;  // 1 => int32, 0 => int64
    }
}

__device__ __forceinline__ int edge_at(const void* ei, int is32, long long pos) {
    return is32 ? ((const int*)ei)[pos] : (int)(((const long long*)ei)[pos]);
}

__global__ void k_zero_i32(int* p, int n) {
    int i = blockIdx.x * blockDim.x + threadIdx.x;
    if (i < n) p[i] = 0;
}

__global__ void k_count(const void* ei, const int* flag, int E, int N, int* deg) {
    int e = blockIdx.x * blockDim.x + threadIdx.x;
    int Etot = E + N;
    if (e >= Etot) return;
    int is32 = *flag;
    int dst = (e < E) ? edge_at(ei, is32, (long long)E + e) : (e - E);
    atomicAdd(&deg[dst], 1);
}

// ---------------- multi-block exclusive scan --------------------------------
#define SCAN_BLOCKS 256
#define SCAN_TPB    256

__global__ __launch_bounds__(SCAN_TPB) void k_scan1(const int* __restrict__ deg,
                                                    int* __restrict__ bsum, int N) {
    __shared__ int sdata[SCAN_TPB];
    int b = blockIdx.x;
    int chunk = (N + SCAN_BLOCKS - 1) / SCAN_BLOCKS;
    int start = b * chunk;
    int end = start + chunk;
    if (start > N) start = N;
    if (end > N) end = N;
    int s = 0;
    for (int i = start + threadIdx.x; i < end; i += SCAN_TPB) s += deg[i];
    sdata[threadIdx.x] = s;
    __syncthreads();
    for (int o = SCAN_TPB / 2; o; o >>= 1) {
        if (threadIdx.x < o) sdata[threadIdx.x] += sdata[threadIdx.x + o];
        __syncthreads();
    }
    if (threadIdx.x == 0) bsum[b] = sdata[0];
}

__global__ __launch_bounds__(SCAN_BLOCKS) void k_scan2(const int* __restrict__ bsum,
                                                       int* __restrict__ bbase,
                                                       int* __restrict__ off_last) {
    __shared__ int sdata[SCAN_BLOCKS];
    int t = threadIdx.x;
    sdata[t] = bsum[t];
    __syncthreads();
    for (int o = 1; o < SCAN_BLOCKS; o <<= 1) {
        int v = (t >= o) ? sdata[t - o] : 0;
        __syncthreads();
        sdata[t] += v;
        __syncthreads();
    }
    bbase[t] = (t == 0) ? 0 : sdata[t - 1];
    if (t == SCAN_BLOCKS - 1) *off_last = sdata[t];
}

__global__ __launch_bounds__(SCAN_TPB) void k_scan3(const int* __restrict__ deg,
                                                    const int* __restrict__ bbase,
                                                    int* __restrict__ off,
                                                    int* __restrict__ cur, int N) {
    __shared__ int sdata[SCAN_TPB];
    int b = blockIdx.x;
    int chunk = (N + SCAN_BLOCKS - 1) / SCAN_BLOCKS;
    int start = b * chunk;
    int end = start + chunk;
    if (start > N) start = N;
    if (end > N) end = N;
    int base = bbase[b];
    for (int i0 = start; i0 < end; i0 += SCAN_TPB) {
        int i = i0 + threadIdx.x;
        int v = (i < end) ? deg[i] : 0;
        sdata[threadIdx.x] = v;
        __syncthreads();
        for (int o = 1; o < SCAN_TPB; o <<= 1) {
            int u = (threadIdx.x >= o) ? sdata[threadIdx.x - o] : 0;
            __syncthreads();
            sdata[threadIdx.x] += u;
            __syncthreads();
        }
        if (i < end) {
            int excl = base + sdata[threadIdx.x] - v;
            off[i] = excl;
            cur[i] = excl;
        }
        base += sdata[SCAN_TPB - 1];
        __syncthreads();
    }
}

__global__ void k_fill(const void* ei, const int* flag, int E, int N, int* cur, int* csr) {
    int e = blockIdx.x * blockDim.x + threadIdx.x;
    int Etot = E + N;
    if (e >= Etot) return;
    int is32 = *flag;
    int src, dst;
    if (e < E) {
        src = edge_at(ei, is32, e);
        dst = edge_at(ei, is32, (long long)E + e);
    } else {
        src = e - E;
        dst = e - E;
    }
    int pos = atomicAdd(&cur[dst], 1);
    csr[pos] = src;
}

// ---------------- operand pre-split kernels ---------------------------------
// W [nblk][K][128] fp32 -> Bt hi/lo [nblk][128][K] bf16 (transposed)
__global__ void k_splitw(const float* __restrict__ W, u16* __restrict__ hi,
                         u16* __restrict__ lo, int nblk, int K) {
    int idx = blockIdx.x * blockDim.x + threadIdx.x;
    int total = nblk * K * 128;
    if (idx >= total) return;
    int blk = idx / (K * 128);
    int rem = idx - blk * K * 128;
    int k = rem >> 7, col = rem & 127;
    float v = W[idx];
    u16 h = f2b_rne(v);
    size_t o = (size_t)blk * 128 * K + (size_t)col * K + k;
    hi[o] = h;
    lo[o] = f2b_rne(v - b2f(h));
}

__global__ void k_splitx(const float* __restrict__ X, u16* __restrict__ hi,
                         u16* __restrict__ lo, int n) {
    int i = blockIdx.x * blockDim.x + threadIdx.x;
    if (i >= n) return;
    float v = X[i];
    u16 h = f2b_rne(v);
    hi[i] = h;
    lo[i] = f2b_rne(v - b2f(h));
}

// ---------------- split-bf16 MFMA GEMM (pre-split operands) -----------------
// 128x128 block tile, 4 waves (2x2 of 64x64), BK=32.
// MODE 0 (head GEMM, K=128, grid.y=4 heads): writes Hb = fp16(H) and the
//   fused attention scores ssrc/sdst[yb][row] (reduced in-block).
// MODE 1 (enc lin GEMM): bias+relu, writes Cb1/Cb2 = bf16 hi/lo [M][128].
// MODE 2 (dec lin GEMM): bias+relu, writes C fp32 [M][128] (d_out).
template <int MODE>
__global__ __launch_bounds__(256) void k_gemm_bf(
    const u16* __restrict__ Ahi, const u16* __restrict__ Alo, int lda,
    const u16* __restrict__ Bthi, const u16* __restrict__ Btlo,
    const float* __restrict__ bias,
    const float* __restrict__ asrc, const float* __restrict__ adst,
    float* __restrict__ C, u16* __restrict__ Cb1, u16* __restrict__ Cb2,
    float* __restrict__ ssrc, float* __restrict__ sdst,
    int ldc, int M, int K)
{
    __shared__ alignas(16) char smem[32768];
    const int AHI = 0, ALO = 8192, BHI = 16384, BLO = 24576;
    int tid = threadIdx.x;
    int bm0 = blockIdx.x * 128;
    int yb = blockIdx.y;

    int wid = tid >> 6, lane = tid & 63;
    int wr = wid >> 1, wc = wid & 1;
    int fr = lane & 15, g = lane >> 4;

    f32x4 acc[4][4] = {};

    int arow = tid >> 1, ahalf = tid & 1;
    bool ain = (bm0 + arow) < M;
    const u16* aph = Ahi + (size_t)(bm0 + arow) * lda + ahalf * 16;
    const u16* apl = Alo + (size_t)(bm0 + arow) * lda + ahalf * 16;
    int bcol = tid & 127, bhalf = tid >> 7;
    const u16* bph = Bthi + (size_t)yb * 128 * K + (size_t)bcol * K + bhalf * 16;
    const u16* bpl = Btlo + (size_t)yb * 128 * K + (size_t)bcol * K + bhalf * 16;

    int abase = arow * 64 + ahalf * 32;
    int asw = (arow & 7) << 4;
    int bbase = bcol * 64 + bhalf * 32;
    int bsw = (bcol & 7) << 4;

    for (int k0 = 0; k0 < K; k0 += 32) {
        bf16x8 va0, va1, vl0, vl1;
        if (ain) {
            va0 = *(const bf16x8*)(aph + k0);
            va1 = *(const bf16x8*)(aph + k0 + 8);
            vl0 = *(const bf16x8*)(apl + k0);
            vl1 = *(const bf16x8*)(apl + k0 + 8);
        } else {
            va0 = (bf16x8)0; va1 = (bf16x8)0; vl0 = (bf16x8)0; vl1 = (bf16x8)0;
        }
        bf16x8 vb0 = *(const bf16x8*)(bph + k0);
        bf16x8 vb1 = *(const bf16x8*)(bph + k0 + 8);
        bf16x8 vm0 = *(const bf16x8*)(bpl + k0);
        bf16x8 vm1 = *(const bf16x8*)(bpl + k0 + 8);

        *(bf16x8*)(smem + AHI + ((abase +  0) ^ asw)) = va0;
        *(bf16x8*)(smem + AHI + ((abase + 16) ^ asw)) = va1;
        *(bf16x8*)(smem + ALO + ((abase +  0) ^ asw)) = vl0;
        *(bf16x8*)(smem + ALO + ((abase + 16) ^ asw)) = vl1;
        *(bf16x8*)(smem + BHI + ((bbase +  0) ^ bsw)) = vb0;
        *(bf16x8*)(smem + BHI + ((bbase + 16) ^ bsw)) = vb1;
        *(bf16x8*)(smem + BLO + ((bbase +  0) ^ bsw)) = vm0;
        *(bf16x8*)(smem + BLO + ((bbase + 16) ^ bsw)) = vm1;

        __syncthreads();

        bf16x8 ah[4], al[4], bh[4], bl[4];
#pragma unroll
        for (int mi = 0; mi < 4; ++mi) {
            int r = wr * 64 + mi * 16 + fr;
            int off = (r * 64 + g * 16) ^ ((r & 7) << 4);
            ah[mi] = *(bf16x8*)(smem + AHI + off);
            al[mi] = *(bf16x8*)(smem + ALO + off);
        }
#pragma unroll
        for (int nj = 0; nj < 4; ++nj) {
            int c = wc * 64 + nj * 16 + fr;
            int off = (c * 64 + g * 16) ^ ((c & 7) << 4);
            bh[nj] = *(bf16x8*)(smem + BHI + off);
            bl[nj] = *(bf16x8*)(smem + BLO + off);
        }

#pragma unroll
        for (int mi = 0; mi < 4; ++mi)
#pragma unroll
            for (int nj = 0; nj < 4; ++nj) {
                acc[mi][nj] = __builtin_amdgcn_mfma_f32_16x16x32_bf16(ah[mi], bh[nj], acc[mi][nj], 0, 0, 0);
                acc[mi][nj] = __builtin_amdgcn_mfma_f32_16x16x32_bf16(ah[mi], bl[nj], acc[mi][nj], 0, 0, 0);
                acc[mi][nj] = __builtin_amdgcn_mfma_f32_16x16x32_bf16(al[mi], bh[nj], acc[mi][nj], 0, 0, 0);
            }
        __syncthreads();
    }

    // ---- main output stores ----
#pragma unroll
    for (int mi = 0; mi < 4; ++mi) {
#pragma unroll
        for (int q = 0; q < 4; ++q) {
            int r = bm0 + wr * 64 + mi * 16 + g * 4 + q;
            if (r >= M) continue;
#pragma unroll
            for (int nj = 0; nj < 4; ++nj) {
                int clocal = wc * 64 + nj * 16 + fr;
                float v = acc[mi][nj][q];
                if (MODE == 0) {
                    size_t idx = (size_t)r * ldc + yb * 128 + clocal;
                    __half hv = __float2half(v);
                    Cb1[idx] = *(u16*)&hv;
                } else if (MODE == 1) {
                    v += bias[clocal];
                    v = fmaxf(v, 0.f);
                    size_t idx = (size_t)r * ldc + clocal;
                    u16 h = f2b_rne(v);
                    Cb1[idx] = h;
                    Cb2[idx] = f2b_rne(v - b2f(h));
                } else {
                    v += bias[clocal];
                    v = fmaxf(v, 0.f);
                    C[(size_t)r * ldc + clocal] = v;
                }
            }
        }
    }

    // ---- MODE 0: fused attention scores for head yb ----
    if (MODE == 0) {
        float* sred = (float*)smem;  // [128 rows][2 wc][2 which]
        float asv[4], adv[4];
        const float* ap = asrc + yb * FDIM;
        const float* dp = adst + yb * FDIM;
#pragma unroll
        for (int nj = 0; nj < 4; ++nj) {
            int c = wc * 64 + nj * 16 + fr;
            asv[nj] = ap[c];
            adv[nj] = dp[c];
        }
#pragma unroll
        for (int mi = 0; mi < 4; ++mi) {
#pragma unroll
            for (int q = 0; q < 4; ++q) {
                float ps = 0.f, pd = 0.f;
#pragma unroll
                for (int nj = 0; nj < 4; ++nj) {
                    ps += acc[mi][nj][q] * asv[nj];
                    pd += acc[mi][nj][q] * adv[nj];
                }
#pragma unroll
                for (int o = 1; o < 16; o <<= 1) {
                    ps += __shfl_xor(ps, o);
                    pd += __shfl_xor(pd, o);
                }
                if (fr == 0) {
                    int row128 = wr * 64 + mi * 16 + g * 4 + q;
                    sred[(row128 * 2 + wc) * 2 + 0] = ps;
                    sred[(row128 * 2 + wc) * 2 + 1] = pd;
                }
            }
        }
        __syncthreads();
        {
            int rg = tid >> 1;          // 0..127
            int which = tid & 1;
            int r = bm0 + rg;
            if (r < M) {
                float v = sred[(rg * 2 + 0) * 2 + which] + sred[(rg * 2 + 1) * 2 + which];
                float* dstp = which ? sdst : ssrc;
                dstp[(size_t)yb * M + r] = v;
            }
        }
    }
}

// ---------------- segment softmax + fp16 gather aggregate -------------------
// 1 wave/node. Lane l owns columns [8l, 8l+8) (head = l>>4). No max pass:
// scores are O(1) (max |e| ~ 8), exp(e) safe in fp32; softmax shift-invariant.
__global__ __launch_bounds__(64) void k_aggregate(
    const u16* __restrict__ Hb, const int* __restrict__ off,
    const int* __restrict__ csr, const float* __restrict__ ssrc,
    const float* __restrict__ sdst, const float* __restrict__ bvec,
    u16* __restrict__ Ghi, u16* __restrict__ Glo, int N) {
    int n = blockIdx.x;
    int lane = threadIdx.x;
    int o0 = off[n], o1 = off[n + 1];
    int h = lane >> 4;
    int col0 = lane * 8;
    float sdh = sdst[(size_t)h * N + n];
    const float* ssrc_h = ssrc + (size_t)h * N;
    float denom = 0.f;
    float acc[8] = {0.f, 0.f, 0.f, 0.f, 0.f, 0.f, 0.f, 0.f};
    for (int i = o0; i < o1; ++i) {
        int s = csr[i];
        float e = ssrc_h[s] + sdh;
        e = e >= 0.f ? e : 0.2f * e;
        float ew = __expf(e);
        denom += ew;
        uint4 hv = *(const uint4*)&Hb[(size_t)s * HCAT + col0];
        const __half2* hp = (const __half2*)&hv;
#pragma unroll
        for (int j = 0; j < 4; ++j) {
            float2 f = __half22float2(hp[j]);
            acc[2 * j]     += ew * f.x;
            acc[2 * j + 1] += ew * f.y;
        }
    }
    float inv = 1.f / denom;
    u16 hs[8], ls[8];
#pragma unroll
    for (int k = 0; k < 8; ++k) {
        int col = col0 + k;
        float v = acc[k] * inv + bvec[h * FDIM + (col & 127)];
        u16 hbits = f2b_rne(v);
        hs[k] = hbits;
        ls[k] = f2b_rne(v - b2f(hbits));
    }
    *(uint4*)&Ghi[(size_t)n * HCAT + col0] = *(uint4*)hs;
    *(uint4*)&Glo[(size_t)n * HCAT + col0] = *(uint4*)ls;
}

// ---------------------------------------------------------------------------
extern "C" void kernel_launch(void* const* d_in, const int* in_sizes, int n_in,
                              void* d_out, int out_size, void* d_ws, size_t ws_size,
                              hipStream_t stream) {
    const float* x = (const float*)d_in[0];
    const void* ei = d_in[1];
    const float* encW = (const float*)d_in[2];
    const float* enc_asrc = (const float*)d_in[3];
    const float* enc_adst = (const float*)d_in[4];
    const float* enc_b = (const float*)d_in[5];
    const float* enc_linW = (const float*)d_in[6];
    const float* enc_linb = (const float*)d_in[7];
    const float* decW = (const float*)d_in[8];
    const float* dec_asrc = (const float*)d_in[9];
    const float* dec_adst = (const float*)d_in[10];
    const float* dec_b = (const float*)d_in[11];
    const float* dec_linW = (const float*)d_in[12];
    const float* dec_linb = (const float*)d_in[13];

    int N = in_sizes[0] / FDIM;
    int E = in_sizes[1] / 2;
    int Etot = E + N;

    char* w = (char*)d_ws;
    size_t o = 0;
    auto alloc = [&](size_t bytes) -> char* {
        char* p = w + o;
        o += (bytes + 255) & ~(size_t)255;
        return p;
    };
    int* flag = (int*)alloc(4);
    int* deg = (int*)alloc((size_t)N * 4);
    int* off = (int*)alloc((size_t)(N + 1) * 4);
    int* cur = (int*)alloc((size_t)N * 4);
    int* csr = (int*)alloc((size_t)Etot * 4);
    int* bsum = (int*)alloc(SCAN_BLOCKS * 4);
    int* bbase = (int*)alloc(SCAN_BLOCKS * 4);
    float* ssrc = (float*)alloc((size_t)HEADS * N * 4);
    float* sdst = (float*)alloc((size_t)HEADS * N * 4);
    u16* Ghi = (u16*)alloc((size_t)N * HCAT * 2);
    u16* Glo = (u16*)alloc((size_t)N * HCAT * 2);
    u16* Hb = (u16*)alloc((size_t)N * HCAT * 2);
    u16* xhi = (u16*)alloc((size_t)N * FDIM * 2);
    u16* xlo = (u16*)alloc((size_t)N * FDIM * 2);
    u16* X2hi = (u16*)alloc((size_t)N * FDIM * 2);
    u16* X2lo = (u16*)alloc((size_t)N * FDIM * 2);
    u16* encWt_h = (u16*)alloc((size_t)HEADS * FDIM * FDIM * 2);
    u16* encWt_l = (u16*)alloc((size_t)HEADS * FDIM * FDIM * 2);
    u16* linWt_h = (u16*)alloc((size_t)HCAT * FDIM * 2);
    u16* linWt_l = (u16*)alloc((size_t)HCAT * FDIM * 2);
    u16* decWt_h = (u16*)alloc((size_t)HEADS * FDIM * FDIM * 2);
    u16* decWt_l = (u16*)alloc((size_t)HEADS * FDIM * FDIM * 2);
    u16* dlinWt_h = (u16*)alloc((size_t)HCAT * FDIM * 2);
    u16* dlinWt_l = (u16*)alloc((size_t)HCAT * FDIM * 2);
    (void)ws_size;

    // CSR build
    k_detect<<<1, 64, 0, stream>>>(ei, E, N, flag);
    k_zero_i32<<<(N + 255) / 256, 256, 0, stream>>>(deg, N);
    k_count<<<(Etot + 255) / 256, 256, 0, stream>>>(ei, flag, E, N, deg);
    k_scan1<<<SCAN_BLOCKS, SCAN_TPB, 0, stream>>>(deg, bsum, N);
    k_scan2<<<1, SCAN_BLOCKS, 0, stream>>>(bsum, bbase, off + N);
    k_scan3<<<SCAN_BLOCKS, SCAN_TPB, 0, stream>>>(deg, bbase, off, cur, N);
    k_fill<<<(Etot + 255) / 256, 256, 0, stream>>>(ei, flag, E, N, cur, csr);

    // operand pre-splits
    int wtot = HEADS * FDIM * FDIM;
    k_splitw<<<(wtot + 255) / 256, 256, 0, stream>>>(encW, encWt_h, encWt_l, HEADS, FDIM);
    k_splitw<<<(wtot + 255) / 256, 256, 0, stream>>>(enc_linW, linWt_h, linWt_l, 1, HCAT);
    k_splitw<<<(wtot + 255) / 256, 256, 0, stream>>>(decW, decWt_h, decWt_l, HEADS, FDIM);
    k_splitw<<<(wtot + 255) / 256, 256, 0, stream>>>(dec_linW, dlinWt_h, dlinWt_l, 1, HCAT);
    k_splitx<<<(N * FDIM + 255) / 256, 256, 0, stream>>>(x, xhi, xlo, N * FDIM);

    int mblocks = (N + 127) / 128;

    // ---- encoder ----
    k_gemm_bf<0><<<dim3(mblocks, 4), 256, 0, stream>>>(
        xhi, xlo, FDIM, encWt_h, encWt_l, nullptr, enc_asrc, enc_adst,
        nullptr, Hb, nullptr, ssrc, sdst, HCAT, N, FDIM);
    k_aggregate<<<N, 64, 0, stream>>>(Hb, off, csr, ssrc, sdst, enc_b, Ghi, Glo, N);
    k_gemm_bf<1><<<dim3(mblocks, 1), 256, 0, stream>>>(
        Ghi, Glo, HCAT, linWt_h, linWt_l, enc_linb, nullptr, nullptr,
        nullptr, X2hi, X2lo, nullptr, nullptr, FDIM, N, HCAT);

    // ---- decoder ----
    k_gemm_bf<0><<<dim3(mblocks, 4), 256, 0, stream>>>(
        X2hi, X2lo, FDIM, decWt_h, decWt_l, nullptr, dec_asrc, dec_adst,
        nullptr, Hb, nullptr, ssrc, sdst, HCAT, N, FDIM);
    k_aggregate<<<N, 64, 0, stream>>>(Hb, off, csr, ssrc, sdst, dec_b, Ghi, Glo, N);
    k_gemm_bf<2><<<dim3(mblocks, 1), 256, 0, stream>>>(
        Ghi, Glo, HCAT, dlinWt_h, dlinWt_l, dec_linb, nullptr, nullptr,
        (float*)d_out, nullptr, nullptr, nullptr, nullptr, FDIM, N, HCAT);
}

// Round 6
// 533.630 us; speedup vs baseline: 2.2567x; 1.1137x over previous
//
#include <hip/hip_runtime.h>
#include <hip/hip_fp16.h>
#include <cstdint>
#include <cstddef>

// ---------------------------------------------------------------------------
// GraphAutoencoder: 2 x [4-head GATConv(128->128) -> concat -> Linear(512->128) -> ReLU]
// N=50000, E=800000 (+N self-loops). fp32 in/out.
// GEMMs: fp16 MFMA, A = fp16 activations (single), B = fp16 hi/lo split
// weights (2 products). Scores fused into head-GEMM epilogue.
// Aggregate: fp16 gather, unroll-4, single fp16 output.
// ---------------------------------------------------------------------------

#define FDIM   128
#define HEADS  4
#define HCAT   512

typedef unsigned short u16;
typedef __attribute__((ext_vector_type(4))) float f32x4;
typedef __attribute__((ext_vector_type(8))) _Float16 f16x8;

__device__ __forceinline__ u16 f2h_bits(float f) {
    _Float16 h = (_Float16)f;
    return *(u16*)&h;
}

// ---------------- edge dtype detection (int64 vs int32) ---------------------
__global__ void k_detect(const void* ei, int E, int N, int* flag) {
    if (threadIdx.x == 0 && blockIdx.x == 0) {
        const long long* p = (const long long*)ei;
        int bad = 0;
        int n = E < 64 ? E : 64;
        for (int i = 0; i < n; ++i) {
            long long v = p[i];
            if (v < 0 || v >= (long long)N) bad = 1;
        }
        *flag = bad;  // 1 => int32, 0 => int64
    }
}

__device__ __forceinline__ int edge_at(const void* ei, int is32, long long pos) {
    return is32 ? ((const int*)ei)[pos] : (int)(((const long long*)ei)[pos]);
}

__global__ void k_zero_i32(int* p, int n) {
    int i = blockIdx.x * blockDim.x + threadIdx.x;
    if (i < n) p[i] = 0;
}

__global__ void k_count(const void* ei, const int* flag, int E, int N, int* deg) {
    int e = blockIdx.x * blockDim.x + threadIdx.x;
    int Etot = E + N;
    if (e >= Etot) return;
    int is32 = *flag;
    int dst = (e < E) ? edge_at(ei, is32, (long long)E + e) : (e - E);
    atomicAdd(&deg[dst], 1);
}

// ---------------- multi-block exclusive scan --------------------------------
#define SCAN_BLOCKS 256
#define SCAN_TPB    256

__global__ __launch_bounds__(SCAN_TPB) void k_scan1(const int* __restrict__ deg,
                                                    int* __restrict__ bsum, int N) {
    __shared__ int sdata[SCAN_TPB];
    int b = blockIdx.x;
    int chunk = (N + SCAN_BLOCKS - 1) / SCAN_BLOCKS;
    int start = b * chunk;
    int end = start + chunk;
    if (start > N) start = N;
    if (end > N) end = N;
    int s = 0;
    for (int i = start + threadIdx.x; i < end; i += SCAN_TPB) s += deg[i];
    sdata[threadIdx.x] = s;
    __syncthreads();
    for (int o = SCAN_TPB / 2; o; o >>= 1) {
        if (threadIdx.x < o) sdata[threadIdx.x] += sdata[threadIdx.x + o];
        __syncthreads();
    }
    if (threadIdx.x == 0) bsum[b] = sdata[0];
}

__global__ __launch_bounds__(SCAN_BLOCKS) void k_scan2(const int* __restrict__ bsum,
                                                       int* __restrict__ bbase,
                                                       int* __restrict__ off_last) {
    __shared__ int sdata[SCAN_BLOCKS];
    int t = threadIdx.x;
    sdata[t] = bsum[t];
    __syncthreads();
    for (int o = 1; o < SCAN_BLOCKS; o <<= 1) {
        int v = (t >= o) ? sdata[t - o] : 0;
        __syncthreads();
        sdata[t] += v;
        __syncthreads();
    }
    bbase[t] = (t == 0) ? 0 : sdata[t - 1];
    if (t == SCAN_BLOCKS - 1) *off_last = sdata[t];
}

__global__ __launch_bounds__(SCAN_TPB) void k_scan3(const int* __restrict__ deg,
                                                    const int* __restrict__ bbase,
                                                    int* __restrict__ off,
                                                    int* __restrict__ cur, int N) {
    __shared__ int sdata[SCAN_TPB];
    int b = blockIdx.x;
    int chunk = (N + SCAN_BLOCKS - 1) / SCAN_BLOCKS;
    int start = b * chunk;
    int end = start + chunk;
    if (start > N) start = N;
    if (end > N) end = N;
    int base = bbase[b];
    for (int i0 = start; i0 < end; i0 += SCAN_TPB) {
        int i = i0 + threadIdx.x;
        int v = (i < end) ? deg[i] : 0;
        sdata[threadIdx.x] = v;
        __syncthreads();
        for (int o = 1; o < SCAN_TPB; o <<= 1) {
            int u = (threadIdx.x >= o) ? sdata[threadIdx.x - o] : 0;
            __syncthreads();
            sdata[threadIdx.x] += u;
            __syncthreads();
        }
        if (i < end) {
            int excl = base + sdata[threadIdx.x] - v;
            off[i] = excl;
            cur[i] = excl;
        }
        base += sdata[SCAN_TPB - 1];
        __syncthreads();
    }
}

__global__ void k_fill(const void* ei, const int* flag, int E, int N, int* cur, int* csr) {
    int e = blockIdx.x * blockDim.x + threadIdx.x;
    int Etot = E + N;
    if (e >= Etot) return;
    int is32 = *flag;
    int src, dst;
    if (e < E) {
        src = edge_at(ei, is32, e);
        dst = edge_at(ei, is32, (long long)E + e);
    } else {
        src = e - E;
        dst = e - E;
    }
    int pos = atomicAdd(&cur[dst], 1);
    csr[pos] = src;
}

// ---------------- operand prep ----------------------------------------------
// W [nblk][K][128] fp32 -> Wt hi/lo fp16 [nblk][128][K] (transposed)
__global__ void k_splitw(const float* __restrict__ W, u16* __restrict__ hi,
                         u16* __restrict__ lo, int nblk, int K) {
    int idx = blockIdx.x * blockDim.x + threadIdx.x;
    int total = nblk * K * 128;
    if (idx >= total) return;
    int blk = idx / (K * 128);
    int rem = idx - blk * K * 128;
    int k = rem >> 7, col = rem & 127;
    float v = W[idx];
    _Float16 hh = (_Float16)v;
    _Float16 ll = (_Float16)(v - (float)hh);
    size_t o = (size_t)blk * 128 * K + (size_t)col * K + k;
    hi[o] = *(u16*)&hh;
    lo[o] = *(u16*)&ll;
}

__global__ void k_cvt_f16(const float* __restrict__ X, u16* __restrict__ out, int n) {
    int i = blockIdx.x * blockDim.x + threadIdx.x;
    if (i >= n) return;
    out[i] = f2h_bits(X[i]);
}

// ---------------- fp16 MFMA GEMM --------------------------------------------
// C[M x ncolblk*128] = A[M x K] * B. A: fp16 [M][lda]. Bt: fp16 hi/lo
// [ncolblk][128][K]. 128x128 block tile, 4 waves (2x2 of 64x64), BK=32.
// 2 MFMA per (mi,nj) per K-step: a*(bh) + a*(bl).
// MODE 0 (head GEMM): writes Hb = fp16(H) + fused scores ssrc/sdst[yb][row].
// MODE 1 (enc lin GEMM): bias+relu, writes Cb1 = fp16 [M][128].
// MODE 2 (dec lin GEMM): bias+relu, writes C fp32 [M][128] (d_out).
template <int MODE>
__global__ __launch_bounds__(256) void k_gemm_f16(
    const u16* __restrict__ A, int lda,
    const u16* __restrict__ Bthi, const u16* __restrict__ Btlo,
    const float* __restrict__ bias,
    const float* __restrict__ asrc, const float* __restrict__ adst,
    float* __restrict__ C, u16* __restrict__ Cb1,
    float* __restrict__ ssrc, float* __restrict__ sdst,
    int ldc, int M, int K)
{
    __shared__ alignas(16) char smem[24576];
    const int ASH = 0, BHI = 8192, BLO = 16384;
    int tid = threadIdx.x;
    int bm0 = blockIdx.x * 128;
    int yb = blockIdx.y;

    int wid = tid >> 6, lane = tid & 63;
    int wr = wid >> 1, wc = wid & 1;
    int fr = lane & 15, g = lane >> 4;

    f32x4 acc[4][4] = {};

    int arow = tid >> 1, ahalf = tid & 1;
    bool ain = (bm0 + arow) < M;
    const u16* aptr = A + (size_t)(bm0 + arow) * lda + ahalf * 16;
    int bcol = tid & 127, bhalf = tid >> 7;
    const u16* bph = Bthi + (size_t)yb * 128 * K + (size_t)bcol * K + bhalf * 16;
    const u16* bpl = Btlo + (size_t)yb * 128 * K + (size_t)bcol * K + bhalf * 16;

    int abase = arow * 64 + ahalf * 32;
    int asw = (arow & 7) << 4;
    int bbase = bcol * 64 + bhalf * 32;
    int bsw = (bcol & 7) << 4;

    for (int k0 = 0; k0 < K; k0 += 32) {
        uint4 va0, va1;
        if (ain) {
            va0 = *(const uint4*)(aptr + k0);
            va1 = *(const uint4*)(aptr + k0 + 8);
        } else {
            va0 = make_uint4(0, 0, 0, 0);
            va1 = make_uint4(0, 0, 0, 0);
        }
        uint4 vb0 = *(const uint4*)(bph + k0);
        uint4 vb1 = *(const uint4*)(bph + k0 + 8);
        uint4 vm0 = *(const uint4*)(bpl + k0);
        uint4 vm1 = *(const uint4*)(bpl + k0 + 8);

        *(uint4*)(smem + ASH + ((abase +  0) ^ asw)) = va0;
        *(uint4*)(smem + ASH + ((abase + 16) ^ asw)) = va1;
        *(uint4*)(smem + BHI + ((bbase +  0) ^ bsw)) = vb0;
        *(uint4*)(smem + BHI + ((bbase + 16) ^ bsw)) = vb1;
        *(uint4*)(smem + BLO + ((bbase +  0) ^ bsw)) = vm0;
        *(uint4*)(smem + BLO + ((bbase + 16) ^ bsw)) = vm1;

        __syncthreads();

        f16x8 af[4], bh[4], bl[4];
#pragma unroll
        for (int mi = 0; mi < 4; ++mi) {
            int r = wr * 64 + mi * 16 + fr;
            int off = (r * 64 + g * 16) ^ ((r & 7) << 4);
            af[mi] = *(f16x8*)(smem + ASH + off);
        }
#pragma unroll
        for (int nj = 0; nj < 4; ++nj) {
            int c = wc * 64 + nj * 16 + fr;
            int off = (c * 64 + g * 16) ^ ((c & 7) << 4);
            bh[nj] = *(f16x8*)(smem + BHI + off);
            bl[nj] = *(f16x8*)(smem + BLO + off);
        }

#pragma unroll
        for (int mi = 0; mi < 4; ++mi)
#pragma unroll
            for (int nj = 0; nj < 4; ++nj) {
                acc[mi][nj] = __builtin_amdgcn_mfma_f32_16x16x32_f16(af[mi], bh[nj], acc[mi][nj], 0, 0, 0);
                acc[mi][nj] = __builtin_amdgcn_mfma_f32_16x16x32_f16(af[mi], bl[nj], acc[mi][nj], 0, 0, 0);
            }
        __syncthreads();
    }

    // ---- main output stores ----
#pragma unroll
    for (int mi = 0; mi < 4; ++mi) {
#pragma unroll
        for (int q = 0; q < 4; ++q) {
            int r = bm0 + wr * 64 + mi * 16 + g * 4 + q;
            if (r >= M) continue;
#pragma unroll
            for (int nj = 0; nj < 4; ++nj) {
                int clocal = wc * 64 + nj * 16 + fr;
                float v = acc[mi][nj][q];
                if (MODE == 0) {
                    Cb1[(size_t)r * ldc + yb * 128 + clocal] = f2h_bits(v);
                } else if (MODE == 1) {
                    v += bias[clocal];
                    v = fmaxf(v, 0.f);
                    Cb1[(size_t)r * ldc + clocal] = f2h_bits(v);
                } else {
                    v += bias[clocal];
                    v = fmaxf(v, 0.f);
                    C[(size_t)r * ldc + clocal] = v;
                }
            }
        }
    }

    // ---- MODE 0: fused attention scores for head yb ----
    if (MODE == 0) {
        float* sred = (float*)smem;  // [128 rows][2 wc][2 which]
        float asv[4], adv[4];
        const float* ap = asrc + yb * FDIM;
        const float* dp = adst + yb * FDIM;
#pragma unroll
        for (int nj = 0; nj < 4; ++nj) {
            int c = wc * 64 + nj * 16 + fr;
            asv[nj] = ap[c];
            adv[nj] = dp[c];
        }
#pragma unroll
        for (int mi = 0; mi < 4; ++mi) {
#pragma unroll
            for (int q = 0; q < 4; ++q) {
                float ps = 0.f, pd = 0.f;
#pragma unroll
                for (int nj = 0; nj < 4; ++nj) {
                    ps += acc[mi][nj][q] * asv[nj];
                    pd += acc[mi][nj][q] * adv[nj];
                }
#pragma unroll
                for (int o = 1; o < 16; o <<= 1) {
                    ps += __shfl_xor(ps, o);
                    pd += __shfl_xor(pd, o);
                }
                if (fr == 0) {
                    int row128 = wr * 64 + mi * 16 + g * 4 + q;
                    sred[(row128 * 2 + wc) * 2 + 0] = ps;
                    sred[(row128 * 2 + wc) * 2 + 1] = pd;
                }
            }
        }
        __syncthreads();
        {
            int rg = tid >> 1;          // 0..127
            int which = tid & 1;
            int r = bm0 + rg;
            if (r < M) {
                float v = sred[(rg * 2 + 0) * 2 + which] + sred[(rg * 2 + 1) * 2 + which];
                float* dstp = which ? sdst : ssrc;
                dstp[(size_t)yb * M + r] = v;
            }
        }
    }
}

// ---------------- segment softmax + fp16 gather aggregate -------------------
// 1 wave/node. Lane l owns columns [8l, 8l+8) (head = l>>4). No max pass
// (scores O(1), exp safe in fp32). Unrolled x4 for memory-level parallelism.
__global__ __launch_bounds__(64) void k_aggregate(
    const u16* __restrict__ Hb, const int* __restrict__ off,
    const int* __restrict__ csr, const float* __restrict__ ssrc,
    const float* __restrict__ sdst, const float* __restrict__ bvec,
    u16* __restrict__ Gh, int N) {
    int n = blockIdx.x;
    int lane = threadIdx.x;
    int o0 = __builtin_amdgcn_readfirstlane(off[n]);
    int o1 = __builtin_amdgcn_readfirstlane(off[n + 1]);
    int h = lane >> 4;
    int col0 = lane * 8;
    float sdh = sdst[(size_t)h * N + n];
    const float* ssrc_h = ssrc + (size_t)h * N;
    float denom = 0.f;
    float acc[8] = {0.f, 0.f, 0.f, 0.f, 0.f, 0.f, 0.f, 0.f};

    auto body = [&](float ew, uint4 hv) {
        const __half2* hp = (const __half2*)&hv;
#pragma unroll
        for (int j = 0; j < 4; ++j) {
            float2 f = __half22float2(hp[j]);
            acc[2 * j]     += ew * f.x;
            acc[2 * j + 1] += ew * f.y;
        }
    };

    int i = o0;
    for (; i + 4 <= o1; i += 4) {
        int s0 = csr[i + 0], s1 = csr[i + 1], s2 = csr[i + 2], s3 = csr[i + 3];
        uint4 v0 = *(const uint4*)&Hb[(size_t)s0 * HCAT + col0];
        uint4 v1 = *(const uint4*)&Hb[(size_t)s1 * HCAT + col0];
        uint4 v2 = *(const uint4*)&Hb[(size_t)s2 * HCAT + col0];
        uint4 v3 = *(const uint4*)&Hb[(size_t)s3 * HCAT + col0];
        float e0 = ssrc_h[s0] + sdh, e1 = ssrc_h[s1] + sdh;
        float e2 = ssrc_h[s2] + sdh, e3 = ssrc_h[s3] + sdh;
        e0 = e0 >= 0.f ? e0 : 0.2f * e0;
        e1 = e1 >= 0.f ? e1 : 0.2f * e1;
        e2 = e2 >= 0.f ? e2 : 0.2f * e2;
        e3 = e3 >= 0.f ? e3 : 0.2f * e3;
        float w0 = __expf(e0), w1 = __expf(e1), w2 = __expf(e2), w3 = __expf(e3);
        denom += (w0 + w1) + (w2 + w3);
        body(w0, v0);
        body(w1, v1);
        body(w2, v2);
        body(w3, v3);
    }
    for (; i < o1; ++i) {
        int s = csr[i];
        uint4 v = *(const uint4*)&Hb[(size_t)s * HCAT + col0];
        float e = ssrc_h[s] + sdh;
        e = e >= 0.f ? e : 0.2f * e;
        float ew = __expf(e);
        denom += ew;
        body(ew, v);
    }

    float inv = 1.f / denom;
    u16 hs[8];
#pragma unroll
    for (int k = 0; k < 8; ++k) {
        int col = col0 + k;
        float v = acc[k] * inv + bvec[h * FDIM + (col & 127)];
        hs[k] = f2h_bits(v);
    }
    *(uint4*)&Gh[(size_t)n * HCAT + col0] = *(uint4*)hs;
}

// ---------------------------------------------------------------------------
extern "C" void kernel_launch(void* const* d_in, const int* in_sizes, int n_in,
                              void* d_out, int out_size, void* d_ws, size_t ws_size,
                              hipStream_t stream) {
    const float* x = (const float*)d_in[0];
    const void* ei = d_in[1];
    const float* encW = (const float*)d_in[2];
    const float* enc_asrc = (const float*)d_in[3];
    const float* enc_adst = (const float*)d_in[4];
    const float* enc_b = (const float*)d_in[5];
    const float* enc_linW = (const float*)d_in[6];
    const float* enc_linb = (const float*)d_in[7];
    const float* decW = (const float*)d_in[8];
    const float* dec_asrc = (const float*)d_in[9];
    const float* dec_adst = (const float*)d_in[10];
    const float* dec_b = (const float*)d_in[11];
    const float* dec_linW = (const float*)d_in[12];
    const float* dec_linb = (const float*)d_in[13];

    int N = in_sizes[0] / FDIM;
    int E = in_sizes[1] / 2;
    int Etot = E + N;

    char* w = (char*)d_ws;
    size_t o = 0;
    auto alloc = [&](size_t bytes) -> char* {
        char* p = w + o;
        o += (bytes + 255) & ~(size_t)255;
        return p;
    };
    int* flag = (int*)alloc(4);
    int* deg = (int*)alloc((size_t)N * 4);
    int* off = (int*)alloc((size_t)(N + 1) * 4);
    int* cur = (int*)alloc((size_t)N * 4);
    int* csr = (int*)alloc((size_t)Etot * 4);
    int* bsum = (int*)alloc(SCAN_BLOCKS * 4);
    int* bbase = (int*)alloc(SCAN_BLOCKS * 4);
    float* ssrc = (float*)alloc((size_t)HEADS * N * 4);
    float* sdst = (float*)alloc((size_t)HEADS * N * 4);
    u16* Gh = (u16*)alloc((size_t)N * HCAT * 2);
    u16* Hb = (u16*)alloc((size_t)N * HCAT * 2);
    u16* xh = (u16*)alloc((size_t)N * FDIM * 2);
    u16* X2h = (u16*)alloc((size_t)N * FDIM * 2);
    u16* encWt_h = (u16*)alloc((size_t)HEADS * FDIM * FDIM * 2);
    u16* encWt_l = (u16*)alloc((size_t)HEADS * FDIM * FDIM * 2);
    u16* linWt_h = (u16*)alloc((size_t)HCAT * FDIM * 2);
    u16* linWt_l = (u16*)alloc((size_t)HCAT * FDIM * 2);
    u16* decWt_h = (u16*)alloc((size_t)HEADS * FDIM * FDIM * 2);
    u16* decWt_l = (u16*)alloc((size_t)HEADS * FDIM * FDIM * 2);
    u16* dlinWt_h = (u16*)alloc((size_t)HCAT * FDIM * 2);
    u16* dlinWt_l = (u16*)alloc((size_t)HCAT * FDIM * 2);
    (void)ws_size;

    // CSR build
    k_detect<<<1, 64, 0, stream>>>(ei, E, N, flag);
    k_zero_i32<<<(N + 255) / 256, 256, 0, stream>>>(deg, N);
    k_count<<<(Etot + 255) / 256, 256, 0, stream>>>(ei, flag, E, N, deg);
    k_scan1<<<SCAN_BLOCKS, SCAN_TPB, 0, stream>>>(deg, bsum, N);
    k_scan2<<<1, SCAN_BLOCKS, 0, stream>>>(bsum, bbase, off + N);
    k_scan3<<<SCAN_BLOCKS, SCAN_TPB, 0, stream>>>(deg, bbase, off, cur, N);
    k_fill<<<(Etot + 255) / 256, 256, 0, stream>>>(ei, flag, E, N, cur, csr);

    // operand prep
    int wtot = HEADS * FDIM * FDIM;
    k_splitw<<<(wtot + 255) / 256, 256, 0, stream>>>(encW, encWt_h, encWt_l, HEADS, FDIM);
    k_splitw<<<(wtot + 255) / 256, 256, 0, stream>>>(enc_linW, linWt_h, linWt_l, 1, HCAT);
    k_splitw<<<(wtot + 255) / 256, 256, 0, stream>>>(decW, decWt_h, decWt_l, HEADS, FDIM);
    k_splitw<<<(wtot + 255) / 256, 256, 0, stream>>>(dec_linW, dlinWt_h, dlinWt_l, 1, HCAT);
    k_cvt_f16<<<(N * FDIM + 255) / 256, 256, 0, stream>>>(x, xh, N * FDIM);

    int mblocks = (N + 127) / 128;

    // ---- encoder ----
    k_gemm_f16<0><<<dim3(mblocks, 4), 256, 0, stream>>>(
        xh, FDIM, encWt_h, encWt_l, nullptr, enc_asrc, enc_adst,
        nullptr, Hb, ssrc, sdst, HCAT, N, FDIM);
    k_aggregate<<<N, 64, 0, stream>>>(Hb, off, csr, ssrc, sdst, enc_b, Gh, N);
    k_gemm_f16<1><<<dim3(mblocks, 1), 256, 0, stream>>>(
        Gh, HCAT, linWt_h, linWt_l, enc_linb, nullptr, nullptr,
        nullptr, X2h, nullptr, nullptr, FDIM, N, HCAT);

    // ---- decoder ----
    k_gemm_f16<0><<<dim3(mblocks, 4), 256, 0, stream>>>(
        X2h, FDIM, decWt_h, decWt_l, nullptr, dec_asrc, dec_adst,
        nullptr, Hb, ssrc, sdst, HCAT, N, FDIM);
    k_aggregate<<<N, 64, 0, stream>>>(Hb, off, csr, ssrc, sdst, dec_b, Gh, N);
    k_gemm_f16<2><<<dim3(mblocks, 1), 256, 0, stream>>>(
        Gh, HCAT, dlinWt_h, dlinWt_l, dec_linb, nullptr, nullptr,
        (float*)d_out, nullptr, nullptr, nullptr, FDIM, N, HCAT);
}

// Round 9
// 532.458 us; speedup vs baseline: 2.2617x; 1.0022x over previous
//
#include <hip/hip_runtime.h>
#include <hip/hip_fp16.h>
#include <cstdint>
#include <cstddef>

// ---------------------------------------------------------------------------
// GraphAutoencoder: 2 x [4-head GATConv(128->128) -> concat -> Linear(512->128) -> ReLU]
// N=50000, E=800000 (+N self-loops). fp32 in/out.
// GEMMs: fp16 MFMA, single-buffer LDS with async-STAGE split (loads for tile
//   k+1 issued before tile k's MFMA; runtime K — compile-time-K is a suspect
//   from rounds 7/8 failures). A = fp16 activations; B = fp16 hi/lo weights.
// Scores fused into head-GEMM epilogue. Aggregate: fp16 gather, unroll-4.
// ---------------------------------------------------------------------------

#define FDIM   128
#define HEADS  4
#define HCAT   512

typedef unsigned short u16;
typedef __attribute__((ext_vector_type(4))) float f32x4;
typedef __attribute__((ext_vector_type(8))) _Float16 f16x8;

__device__ __forceinline__ u16 f2h_bits(float f) {
    _Float16 h = (_Float16)f;
    return *(u16*)&h;
}

// ---------------- edge dtype detection (int64 vs int32) ---------------------
__global__ void k_detect(const void* ei, int E, int N, int* flag) {
    if (threadIdx.x == 0 && blockIdx.x == 0) {
        const long long* p = (const long long*)ei;
        int bad = 0;
        int n = E < 64 ? E : 64;
        for (int i = 0; i < n; ++i) {
            long long v = p[i];
            if (v < 0 || v >= (long long)N) bad = 1;
        }
        *flag = bad;  // 1 => int32, 0 => int64
    }
}

__device__ __forceinline__ int edge_at(const void* ei, int is32, long long pos) {
    return is32 ? ((const int*)ei)[pos] : (int)(((const long long*)ei)[pos]);
}

__global__ void k_zero_i32(int* p, int n) {
    int i = blockIdx.x * blockDim.x + threadIdx.x;
    if (i < n) p[i] = 0;
}

__global__ void k_count(const void* ei, const int* flag, int E, int N, int* deg) {
    int e = blockIdx.x * blockDim.x + threadIdx.x;
    int Etot = E + N;
    if (e >= Etot) return;
    int is32 = *flag;
    int dst = (e < E) ? edge_at(ei, is32, (long long)E + e) : (e - E);
    atomicAdd(&deg[dst], 1);
}

// ---------------- multi-block exclusive scan --------------------------------
#define SCAN_BLOCKS 256
#define SCAN_TPB    256

__global__ __launch_bounds__(SCAN_TPB) void k_scan1(const int* __restrict__ deg,
                                                    int* __restrict__ bsum, int N) {
    __shared__ int sdata[SCAN_TPB];
    int b = blockIdx.x;
    int chunk = (N + SCAN_BLOCKS - 1) / SCAN_BLOCKS;
    int start = b * chunk;
    int end = start + chunk;
    if (start > N) start = N;
    if (end > N) end = N;
    int s = 0;
    for (int i = start + threadIdx.x; i < end; i += SCAN_TPB) s += deg[i];
    sdata[threadIdx.x] = s;
    __syncthreads();
    for (int o = SCAN_TPB / 2; o; o >>= 1) {
        if (threadIdx.x < o) sdata[threadIdx.x] += sdata[threadIdx.x + o];
        __syncthreads();
    }
    if (threadIdx.x == 0) bsum[b] = sdata[0];
}

__global__ __launch_bounds__(SCAN_BLOCKS) void k_scan2(const int* __restrict__ bsum,
                                                       int* __restrict__ bbase,
                                                       int* __restrict__ off_last) {
    __shared__ int sdata[SCAN_BLOCKS];
    int t = threadIdx.x;
    sdata[t] = bsum[t];
    __syncthreads();
    for (int o = 1; o < SCAN_BLOCKS; o <<= 1) {
        int v = (t >= o) ? sdata[t - o] : 0;
        __syncthreads();
        sdata[t] += v;
        __syncthreads();
    }
    bbase[t] = (t == 0) ? 0 : sdata[t - 1];
    if (t == SCAN_BLOCKS - 1) *off_last = sdata[t];
}

__global__ __launch_bounds__(SCAN_TPB) void k_scan3(const int* __restrict__ deg,
                                                    const int* __restrict__ bbase,
                                                    int* __restrict__ off,
                                                    int* __restrict__ cur, int N) {
    __shared__ int sdata[SCAN_TPB];
    int b = blockIdx.x;
    int chunk = (N + SCAN_BLOCKS - 1) / SCAN_BLOCKS;
    int start = b * chunk;
    int end = start + chunk;
    if (start > N) start = N;
    if (end > N) end = N;
    int base = bbase[b];
    for (int i0 = start; i0 < end; i0 += SCAN_TPB) {
        int i = i0 + threadIdx.x;
        int v = (i < end) ? deg[i] : 0;
        sdata[threadIdx.x] = v;
        __syncthreads();
        for (int o = 1; o < SCAN_TPB; o <<= 1) {
            int u = (threadIdx.x >= o) ? sdata[threadIdx.x - o] : 0;
            __syncthreads();
            sdata[threadIdx.x] += u;
            __syncthreads();
        }
        if (i < end) {
            int excl = base + sdata[threadIdx.x] - v;
            off[i] = excl;
            cur[i] = excl;
        }
        base += sdata[SCAN_TPB - 1];
        __syncthreads();
    }
}

__global__ void k_fill(const void* ei, const int* flag, int E, int N, int* cur, int* csr) {
    int e = blockIdx.x * blockDim.x + threadIdx.x;
    int Etot = E + N;
    if (e >= Etot) return;
    int is32 = *flag;
    int src, dst;
    if (e < E) {
        src = edge_at(ei, is32, e);
        dst = edge_at(ei, is32, (long long)E + e);
    } else {
        src = e - E;
        dst = e - E;
    }
    int pos = atomicAdd(&cur[dst], 1);
    csr[pos] = src;
}

// ---------------- operand prep ----------------------------------------------
// W [nblk][K][128] fp32 -> Wt hi/lo fp16 [nblk*128 cols][K] (transposed)
__global__ void k_splitw(const float* __restrict__ W, u16* __restrict__ hi,
                         u16* __restrict__ lo, int nblk, int K) {
    int idx = blockIdx.x * blockDim.x + threadIdx.x;
    int total = nblk * K * 128;
    if (idx >= total) return;
    int blk = idx / (K * 128);
    int rem = idx - blk * K * 128;
    int k = rem >> 7, col = rem & 127;
    float v = W[idx];
    _Float16 hh = (_Float16)v;
    _Float16 ll = (_Float16)(v - (float)hh);
    size_t o = (size_t)blk * 128 * K + (size_t)col * K + k;
    hi[o] = *(u16*)&hh;
    lo[o] = *(u16*)&ll;
}

__global__ void k_cvt_f16(const float* __restrict__ X, u16* __restrict__ out, int n) {
    int i = blockIdx.x * blockDim.x + threadIdx.x;
    if (i >= n) return;
    out[i] = f2h_bits(X[i]);
}

// ---------------- fp16 MFMA GEMM (async-STAGE split, runtime K) -------------
// C[M x gridY*128] = A[M x K] * B. A: fp16 [M][lda]. Bt: fp16 hi/lo
// [cols][K] col-major. 128x128 block tile, 4 waves (2x2 of 64x64), BK=32.
// Loads for tile k+1 issued between the barriers of tile k (hidden by MFMA).
// MODE 0 (head GEMM): writes Hb=fp16 + fused scores ssrc/sdst[yb][row].
// MODE 1 (enc lin): bias+relu -> fp16. MODE 2 (dec lin): bias+relu -> fp32.
template <int MODE>
__global__ __launch_bounds__(256) void k_gemm_f16(
    const u16* __restrict__ A, int lda,
    const u16* __restrict__ Bthi, const u16* __restrict__ Btlo,
    const float* __restrict__ bias,
    const float* __restrict__ asrc, const float* __restrict__ adst,
    float* __restrict__ C, u16* __restrict__ Cb1,
    float* __restrict__ ssrc, float* __restrict__ sdst,
    int ldc, int M, int K)
{
    __shared__ alignas(16) char smem[24576];
    __shared__ float sred[512];
    const int ASH = 0, BHI = 8192, BLO = 16384;
    int tid = threadIdx.x;
    int bm0 = blockIdx.x * 128;
    int yb = blockIdx.y;

    int wid = tid >> 6, lane = tid & 63;
    int wr = wid >> 1, wc = wid & 1;
    int fr = lane & 15, g = lane >> 4;

    f32x4 acc[4][4] = {};

    int arow = tid >> 1, ahalf = tid & 1;
    bool ain = (bm0 + arow) < M;
    const u16* aptr = A + (size_t)(bm0 + arow) * lda + ahalf * 16;
    int bcol = tid & 127, bhalf = tid >> 7;
    const u16* bph = Bthi + (size_t)yb * 128 * K + (size_t)bcol * K + bhalf * 16;
    const u16* bpl = Btlo + (size_t)yb * 128 * K + (size_t)bcol * K + bhalf * 16;

    int abase = arow * 64 + ahalf * 32;
    int asw = (arow & 7) << 4;
    int bbase = bcol * 64 + bhalf * 32;
    int bsw = (bcol & 7) << 4;

    // prologue: issue loads for tile 0
    uint4 va0, va1, vb0, vb1, vm0, vm1;
    if (ain) { va0 = *(const uint4*)(aptr); va1 = *(const uint4*)(aptr + 8); }
    else { va0 = make_uint4(0, 0, 0, 0); va1 = make_uint4(0, 0, 0, 0); }
    vb0 = *(const uint4*)(bph);
    vb1 = *(const uint4*)(bph + 8);
    vm0 = *(const uint4*)(bpl);
    vm1 = *(const uint4*)(bpl + 8);

    for (int k0 = 0; k0 < K; k0 += 32) {
        // stage the already-loaded tile (vmcnt wait lands here, covered by
        // the previous iteration's MFMA block)
        *(uint4*)(smem + ASH + ((abase +  0) ^ asw)) = va0;
        *(uint4*)(smem + ASH + ((abase + 16) ^ asw)) = va1;
        *(uint4*)(smem + BHI + ((bbase +  0) ^ bsw)) = vb0;
        *(uint4*)(smem + BHI + ((bbase + 16) ^ bsw)) = vb1;
        *(uint4*)(smem + BLO + ((bbase +  0) ^ bsw)) = vm0;
        *(uint4*)(smem + BLO + ((bbase + 16) ^ bsw)) = vm1;

        __syncthreads();

        // issue next tile's loads now; consumed at next iteration's stage
        if (k0 + 32 < K) {
            int kn = k0 + 32;
            if (ain) { va0 = *(const uint4*)(aptr + kn); va1 = *(const uint4*)(aptr + kn + 8); }
            else { va0 = make_uint4(0, 0, 0, 0); va1 = make_uint4(0, 0, 0, 0); }
            vb0 = *(const uint4*)(bph + kn);
            vb1 = *(const uint4*)(bph + kn + 8);
            vm0 = *(const uint4*)(bpl + kn);
            vm1 = *(const uint4*)(bpl + kn + 8);
        }

        f16x8 af[4], bh[4], bl[4];
#pragma unroll
        for (int mi = 0; mi < 4; ++mi) {
            int r = wr * 64 + mi * 16 + fr;
            int off = (r * 64 + g * 16) ^ ((r & 7) << 4);
            af[mi] = *(f16x8*)(smem + ASH + off);
        }
#pragma unroll
        for (int nj = 0; nj < 4; ++nj) {
            int c = wc * 64 + nj * 16 + fr;
            int off = (c * 64 + g * 16) ^ ((c & 7) << 4);
            bh[nj] = *(f16x8*)(smem + BHI + off);
            bl[nj] = *(f16x8*)(smem + BLO + off);
        }

#pragma unroll
        for (int mi = 0; mi < 4; ++mi)
#pragma unroll
            for (int nj = 0; nj < 4; ++nj) {
                acc[mi][nj] = __builtin_amdgcn_mfma_f32_16x16x32_f16(af[mi], bh[nj], acc[mi][nj], 0, 0, 0);
                acc[mi][nj] = __builtin_amdgcn_mfma_f32_16x16x32_f16(af[mi], bl[nj], acc[mi][nj], 0, 0, 0);
            }
        __syncthreads();
    }

    // ---- main output stores ----
#pragma unroll
    for (int mi = 0; mi < 4; ++mi) {
#pragma unroll
        for (int q = 0; q < 4; ++q) {
            int r = bm0 + wr * 64 + mi * 16 + g * 4 + q;
            if (r >= M) continue;
#pragma unroll
            for (int nj = 0; nj < 4; ++nj) {
                int c = wc * 64 + nj * 16 + fr;     // col within yb's 128
                float v = acc[mi][nj][q];
                if (MODE == 0) {
                    Cb1[(size_t)r * ldc + yb * 128 + c] = f2h_bits(v);
                } else if (MODE == 1) {
                    v += bias[c];
                    v = fmaxf(v, 0.f);
                    Cb1[(size_t)r * ldc + c] = f2h_bits(v);
                } else {
                    v += bias[c];
                    v = fmaxf(v, 0.f);
                    C[(size_t)r * ldc + c] = v;
                }
            }
        }
    }

    // ---- MODE 0: fused attention scores for head yb ----
    if (MODE == 0) {
        float asv[4], adv[4];
        const float* app = asrc + yb * FDIM;
        const float* dpp = adst + yb * FDIM;
#pragma unroll
        for (int nj = 0; nj < 4; ++nj) {
            int c = wc * 64 + nj * 16 + fr;
            asv[nj] = app[c];
            adv[nj] = dpp[c];
        }
#pragma unroll
        for (int mi = 0; mi < 4; ++mi) {
#pragma unroll
            for (int q = 0; q < 4; ++q) {
                float ps = 0.f, pd = 0.f;
#pragma unroll
                for (int nj = 0; nj < 4; ++nj) {
                    ps += acc[mi][nj][q] * asv[nj];
                    pd += acc[mi][nj][q] * adv[nj];
                }
#pragma unroll
                for (int o = 1; o < 16; o <<= 1) {
                    ps += __shfl_xor(ps, o);
                    pd += __shfl_xor(pd, o);
                }
                if (fr == 0) {
                    int row128 = wr * 64 + mi * 16 + g * 4 + q;
                    sred[(row128 * 2 + wc) * 2 + 0] = ps;
                    sred[(row128 * 2 + wc) * 2 + 1] = pd;
                }
            }
        }
        __syncthreads();
        {
            int rg = tid >> 1;          // 0..127
            int which = tid & 1;
            int r = bm0 + rg;
            if (r < M) {
                float v = sred[(rg * 2 + 0) * 2 + which] + sred[(rg * 2 + 1) * 2 + which];
                float* dstp = which ? sdst : ssrc;
                dstp[(size_t)yb * M + r] = v;
            }
        }
    }
}

// ---------------- segment softmax + fp16 gather aggregate -------------------
// 1 wave/node. Lane l owns columns [8l, 8l+8) (head = l>>4). No max pass
// (scores O(1), exp safe in fp32). Unrolled x4 for memory-level parallelism.
__global__ __launch_bounds__(64) void k_aggregate(
    const u16* __restrict__ Hb, const int* __restrict__ off,
    const int* __restrict__ csr, const float* __restrict__ ssrc,
    const float* __restrict__ sdst, const float* __restrict__ bvec,
    u16* __restrict__ Gh, int N) {
    int n = blockIdx.x;
    int lane = threadIdx.x;
    int o0 = __builtin_amdgcn_readfirstlane(off[n]);
    int o1 = __builtin_amdgcn_readfirstlane(off[n + 1]);
    int h = lane >> 4;
    int col0 = lane * 8;
    float sdh = sdst[(size_t)h * N + n];
    const float* ssrc_h = ssrc + (size_t)h * N;
    float denom = 0.f;
    float acc[8] = {0.f, 0.f, 0.f, 0.f, 0.f, 0.f, 0.f, 0.f};

    auto body = [&](float ew, uint4 hv) {
        const __half2* hp = (const __half2*)&hv;
#pragma unroll
        for (int j = 0; j < 4; ++j) {
            float2 f = __half22float2(hp[j]);
            acc[2 * j]     += ew * f.x;
            acc[2 * j + 1] += ew * f.y;
        }
    };

    int i = o0;
    for (; i + 4 <= o1; i += 4) {
        int s0 = csr[i + 0], s1 = csr[i + 1], s2 = csr[i + 2], s3 = csr[i + 3];
        uint4 v0 = *(const uint4*)&Hb[(size_t)s0 * HCAT + col0];
        uint4 v1 = *(const uint4*)&Hb[(size_t)s1 * HCAT + col0];
        uint4 v2 = *(const uint4*)&Hb[(size_t)s2 * HCAT + col0];
        uint4 v3 = *(const uint4*)&Hb[(size_t)s3 * HCAT + col0];
        float e0 = ssrc_h[s0] + sdh, e1 = ssrc_h[s1] + sdh;
        float e2 = ssrc_h[s2] + sdh, e3 = ssrc_h[s3] + sdh;
        e0 = e0 >= 0.f ? e0 : 0.2f * e0;
        e1 = e1 >= 0.f ? e1 : 0.2f * e1;
        e2 = e2 >= 0.f ? e2 : 0.2f * e2;
        e3 = e3 >= 0.f ? e3 : 0.2f * e3;
        float w0 = __expf(e0), w1 = __expf(e1), w2 = __expf(e2), w3 = __expf(e3);
        denom += (w0 + w1) + (w2 + w3);
        body(w0, v0);
        body(w1, v1);
        body(w2, v2);
        body(w3, v3);
    }
    for (; i < o1; ++i) {
        int s = csr[i];
        uint4 v = *(const uint4*)&Hb[(size_t)s * HCAT + col0];
        float e = ssrc_h[s] + sdh;
        e = e >= 0.f ? e : 0.2f * e;
        float ew = __expf(e);
        denom += ew;
        body(ew, v);
    }

    float inv = 1.f / denom;
    u16 hs[8];
#pragma unroll
    for (int k = 0; k < 8; ++k) {
        int col = col0 + k;
        float v = acc[k] * inv + bvec[h * FDIM + (col & 127)];
        hs[k] = f2h_bits(v);
    }
    *(uint4*)&Gh[(size_t)n * HCAT + col0] = *(uint4*)hs;
}

// ---------------------------------------------------------------------------
extern "C" void kernel_launch(void* const* d_in, const int* in_sizes, int n_in,
                              void* d_out, int out_size, void* d_ws, size_t ws_size,
                              hipStream_t stream) {
    const float* x = (const float*)d_in[0];
    const void* ei = d_in[1];
    const float* encW = (const float*)d_in[2];
    const float* enc_asrc = (const float*)d_in[3];
    const float* enc_adst = (const float*)d_in[4];
    const float* enc_b = (const float*)d_in[5];
    const float* enc_linW = (const float*)d_in[6];
    const float* enc_linb = (const float*)d_in[7];
    const float* decW = (const float*)d_in[8];
    const float* dec_asrc = (const float*)d_in[9];
    const float* dec_adst = (const float*)d_in[10];
    const float* dec_b = (const float*)d_in[11];
    const float* dec_linW = (const float*)d_in[12];
    const float* dec_linb = (const float*)d_in[13];

    int N = in_sizes[0] / FDIM;
    int E = in_sizes[1] / 2;
    int Etot = E + N;

    char* w = (char*)d_ws;
    size_t o = 0;
    auto alloc = [&](size_t bytes) -> char* {
        char* p = w + o;
        o += (bytes + 255) & ~(size_t)255;
        return p;
    };
    int* flag = (int*)alloc(4);
    int* deg = (int*)alloc((size_t)N * 4);
    int* off = (int*)alloc((size_t)(N + 1) * 4);
    int* cur = (int*)alloc((size_t)N * 4);
    int* csr = (int*)alloc((size_t)Etot * 4);
    int* bsum = (int*)alloc(SCAN_BLOCKS * 4);
    int* bbase = (int*)alloc(SCAN_BLOCKS * 4);
    float* ssrc = (float*)alloc((size_t)HEADS * N * 4);
    float* sdst = (float*)alloc((size_t)HEADS * N * 4);
    u16* Gh = (u16*)alloc((size_t)N * HCAT * 2);
    u16* Hb = (u16*)alloc((size_t)N * HCAT * 2);
    u16* xh = (u16*)alloc((size_t)N * FDIM * 2);
    u16* X2h = (u16*)alloc((size_t)N * FDIM * 2);
    u16* encWt_h = (u16*)alloc((size_t)HEADS * FDIM * FDIM * 2);
    u16* encWt_l = (u16*)alloc((size_t)HEADS * FDIM * FDIM * 2);
    u16* linWt_h = (u16*)alloc((size_t)HCAT * FDIM * 2);
    u16* linWt_l = (u16*)alloc((size_t)HCAT * FDIM * 2);
    u16* decWt_h = (u16*)alloc((size_t)HEADS * FDIM * FDIM * 2);
    u16* decWt_l = (u16*)alloc((size_t)HEADS * FDIM * FDIM * 2);
    u16* dlinWt_h = (u16*)alloc((size_t)HCAT * FDIM * 2);
    u16* dlinWt_l = (u16*)alloc((size_t)HCAT * FDIM * 2);
    (void)ws_size;

    // CSR build
    k_detect<<<1, 64, 0, stream>>>(ei, E, N, flag);
    k_zero_i32<<<(N + 255) / 256, 256, 0, stream>>>(deg, N);
    k_count<<<(Etot + 255) / 256, 256, 0, stream>>>(ei, flag, E, N, deg);
    k_scan1<<<SCAN_BLOCKS, SCAN_TPB, 0, stream>>>(deg, bsum, N);
    k_scan2<<<1, SCAN_BLOCKS, 0, stream>>>(bsum, bbase, off + N);
    k_scan3<<<SCAN_BLOCKS, SCAN_TPB, 0, stream>>>(deg, bbase, off, cur, N);
    k_fill<<<(Etot + 255) / 256, 256, 0, stream>>>(ei, flag, E, N, cur, csr);

    // operand prep
    int wtot = HEADS * FDIM * FDIM;
    k_splitw<<<(wtot + 255) / 256, 256, 0, stream>>>(encW, encWt_h, encWt_l, HEADS, FDIM);
    k_splitw<<<(wtot + 255) / 256, 256, 0, stream>>>(enc_linW, linWt_h, linWt_l, 1, HCAT);
    k_splitw<<<(wtot + 255) / 256, 256, 0, stream>>>(decW, decWt_h, decWt_l, HEADS, FDIM);
    k_splitw<<<(wtot + 255) / 256, 256, 0, stream>>>(dec_linW, dlinWt_h, dlinWt_l, 1, HCAT);
    k_cvt_f16<<<(N * FDIM + 255) / 256, 256, 0, stream>>>(x, xh, N * FDIM);

    int mblocks = (N + 127) / 128;

    // ---- encoder ----
    k_gemm_f16<0><<<dim3(mblocks, 4), 256, 0, stream>>>(
        xh, FDIM, encWt_h, encWt_l, nullptr, enc_asrc, enc_adst,
        nullptr, Hb, ssrc, sdst, HCAT, N, FDIM);
    k_aggregate<<<N, 64, 0, stream>>>(Hb, off, csr, ssrc, sdst, enc_b, Gh, N);
    k_gemm_f16<1><<<dim3(mblocks, 1), 256, 0, stream>>>(
        Gh, HCAT, linWt_h, linWt_l, enc_linb, nullptr, nullptr,
        nullptr, X2h, nullptr, nullptr, FDIM, N, HCAT);

    // ---- decoder ----
    k_gemm_f16<0><<<dim3(mblocks, 4), 256, 0, stream>>>(
        X2h, FDIM, decWt_h, decWt_l, nullptr, dec_asrc, dec_adst,
        nullptr, Hb, ssrc, sdst, HCAT, N, FDIM);
    k_aggregate<<<N, 64, 0, stream>>>(Hb, off, csr, ssrc, sdst, dec_b, Gh, N);
    k_gemm_f16<2><<<dim3(mblocks, 1), 256, 0, stream>>>(
        Gh, HCAT, dlinWt_h, dlinWt_l, dec_linb, nullptr, nullptr,
        (float*)d_out, nullptr, nullptr, nullptr, FDIM, N, HCAT);
}